// Round 3
// baseline (400.578 us; speedup 1.0000x reference)
//
#include <hip/hip_runtime.h>

typedef unsigned short u16;
typedef unsigned int   u32;

#define EPSc 1e-5f
#define INFc 1e5f

// all device pointers, passed by value
struct Ptrs {
    const void *h, *x, *v;
    const void *We1, *be1, *We2, *be2;
    const void *Wc1, *bc1, *Wc2, *bc2;
    const void *Wp1, *bp1, *Wp2, *bp2;
    const void *Ws_, *bs_;
    const void *Wn1, *bn1, *Wn2, *bn2;
    const void *Wv1, *bv1, *Wv2, *lg;
    void *out;                 // h (65536) | x (3072) | v (3072), element offsets
    const u32 *flag;           // 1 = buffers are bf16, 0 = buffers are f32
};

__device__ __forceinline__ float bfr(u16 u) { return __uint_as_float(((u32)u) << 16); }
__device__ __forceinline__ u16 f2bf(float f) {
    u32 u = __float_as_uint(f);
    u = u + 0x7fffu + ((u >> 16) & 1u);
    return (u16)(u >> 16);
}
__device__ __forceinline__ float frcp(float x) { return __builtin_amdgcn_rcpf(x); }
__device__ __forceinline__ float silu(float x) { return x * frcp(1.f + __expf(-x)); }
__device__ __forceinline__ float lrelu(float x) { return x > 0.f ? x : 0.2f * x; }

template<int BF16>
__device__ __forceinline__ float LD(const void* p, int i) {
    if constexpr (BF16) return bfr(((const u16*)p)[i]);
    else                return ((const float*)p)[i];
}
template<int BF16>
__device__ __forceinline__ void ST(void* p, int i, float v) {
    if constexpr (BF16) ((u16*)p)[i] = f2bf(v);
    else                ((float*)p)[i] = v;
}

// ---------------- dtype sniffer ----------------
// Decodes first 256 u16s of h as bf16. Real bf16 N(0,1) data: ~256 in range.
// f32 data read as u16 halves: odd halves valid (~128), even halves random
// exponent (~15 pass) -> ~143. Threshold 224 separates cleanly.
__global__ void sniff_kernel(const void* h, u32* flag) {
    if (threadIdx.x == 0) {
        const u16* ph = (const u16*)h;
        int cnt = 0;
        for (int k = 0; k < 256; k++) {
            float v = bfr(ph[k]);
            float a = fabsf(v);
            if (v == 0.f || (a > 1e-6f && a < 1024.f)) cnt++;
        }
        flag[0] = (cnt >= 224) ? 1u : 0u;
    }
}

// block reduction over 256 threads (4 waves) for 4 lanes of data
__device__ __forceinline__ void blk_reduce4(float v[4], bool domax, float* scr, int tid) {
    #pragma unroll
    for (int s2 = 32; s2; s2 >>= 1) {
        #pragma unroll
        for (int u = 0; u < 4; u++) {
            float o = __shfl_xor(v[u], s2);
            v[u] = domax ? fmaxf(v[u], o) : (v[u] + o);
        }
    }
    __syncthreads();               // protect scr from previous use
    if ((tid & 63) == 0) {
        int w = tid >> 6;
        #pragma unroll
        for (int u = 0; u < 4; u++) scr[w * 4 + u] = v[u];
    }
    __syncthreads();
    #pragma unroll
    for (int u = 0; u < 4; u++) {
        float a = scr[0 + u], b = scr[4 + u], c = scr[8 + u], d = scr[12 + u];
        v[u] = domax ? fmaxf(fmaxf(a, b), fmaxf(c, d)) : ((a + b) + (c + d));
    }
}

template<int BF16>
__global__ __launch_bounds__(256) void sake_all(Ptrs p) {
    // uniform early-out if this instantiation doesn't match the data dtype
    if ((p.flag[0] != 0u) != (BF16 != 0)) return;

    const int node = blockIdx.x;      // b*256 + i
    const int i = node & 255;
    const int b = node >> 8;
    const int tid = threadIdx.x;
    const int j = tid;                // this thread's edge partner

    __shared__ u16   s_he[256 * 68];   // h_e rows, bf16, stride 68
    __shared__ u16   s_co[256 * 34];   // coeff rows, bf16, stride 34
    __shared__ float s_xs[256 * 4];    // xs0,xs1,xs2,nrm ; reused as s_part in phase 5
    __shared__ float s_sa[256 * 4];    // semantic logits, later final attention
    __shared__ float s_rows[4 * 64];   // we1_lastrow | be1 | lin_i | h_i
    __shared__ float s_scr[16];
    __shared__ float s_comb[32 * 4];
    __shared__ float s_cn[32];
    __shared__ float s_dv[4];
    __shared__ float s_heagg[256];
    __shared__ float s_t1[64];
    __shared__ float s_hcomb[64];
    __shared__ float s_misc[8];        // 0..2 x_i, 3 vscale, 4..7 exp(log_gamma)

    // ---------- phase A1: stage ----------
    if (tid < 64) {
        s_rows[0 * 64 + tid] = LD<BF16>(p.We1, 128 * 64 + tid);   // last row of W_e1
        s_rows[1 * 64 + tid] = LD<BF16>(p.be1, tid);
        s_rows[3 * 64 + tid] = LD<BF16>(p.h, node * 64 + tid);    // h_i
    } else if (tid < 67) {
        s_misc[tid - 64] = LD<BF16>(p.x, node * 3 + (tid - 64));
    } else if (tid >= 68 && tid < 72) {
        s_misc[4 + (tid - 68)] = __expf(LD<BF16>(p.lg, tid - 68));
    }
    __syncthreads();

    // ---------- phase A2: lin_i + velocity scale ----------
    if (tid < 64) {
        float a = 0.f, w = 0.f;
        #pragma unroll 2
        for (int k = 0; k < 64; k++) {
            float hk = s_rows[3 * 64 + k];
            a += hk * LD<BF16>(p.We1, (64 + k) * 64 + tid);
            w += hk * LD<BF16>(p.Wv1, k * 64 + tid);
        }
        s_rows[2 * 64 + tid] = a;                            // lin_i
        float pv = silu(w + LD<BF16>(p.bv1, tid)) * LD<BF16>(p.Wv2, tid);
        #pragma unroll
        for (int o2 = 32; o2; o2 >>= 1) pv += __shfl_down(pv, o2);
        if (tid == 0) s_misc[3] = pv;                        // vscale
    }
    __syncthreads();

    // ---------- phase B: per-edge pipeline (thread j = edge (i,j)) ----------
    {
        float d0 = LD<BF16>(p.x, (b * 256 + j) * 3 + 0) - s_misc[0];
        float d1 = LD<BF16>(p.x, (b * 256 + j) * 3 + 1) - s_misc[1];
        float d2 = LD<BF16>(p.x, (b * 256 + j) * 3 + 2) - s_misc[2];
        float nrm = sqrtf(d0 * d0 + d1 * d1 + d2 * d2 + EPSc);
        float den = nrm + EPSc;
        float invd = frcp(den * den);
        s_xs[j * 4 + 0] = d0 * invd;
        s_xs[j * 4 + 1] = d1 * invd;
        s_xs[j * 4 + 2] = d2 * invd;
        s_xs[j * 4 + 3] = nrm;

        // lin_j = h_j @ We1[:64]
        float acc[64];
        #pragma unroll
        for (int o = 0; o < 64; o++) acc[o] = 0.f;
        #pragma unroll 2
        for (int k = 0; k < 64; k++) {
            float hk = LD<BF16>(p.h, (b * 256 + j) * 64 + k);
            #pragma unroll
            for (int o = 0; o < 64; o++) acc[o] += hk * LD<BF16>(p.We1, k * 64 + o);
        }
        // spre = silu(lin_j + lin_i + nrm*we1_last + be1)
        #pragma unroll
        for (int o = 0; o < 64; o++)
            acc[o] = silu(acc[o] + s_rows[2 * 64 + o] + nrm * s_rows[0 * 64 + o] + s_rows[1 * 64 + o]);

        // h_e = silu(spre @ We2 + be2), rounded to bf16
        float he[64];
        #pragma unroll
        for (int o = 0; o < 64; o++) he[o] = 0.f;
        #pragma unroll 2
        for (int k = 0; k < 64; k++) {
            float sk = acc[k];
            #pragma unroll
            for (int o = 0; o < 64; o++) he[o] += sk * LD<BF16>(p.We2, k * 64 + o);
        }
        #pragma unroll
        for (int o = 0; o < 64; o++) {
            u16 hb = f2bf(silu(he[o] + LD<BF16>(p.be2, o)));
            he[o] = bfr(hb);
        }
        #pragma unroll
        for (int c = 0; c < 32; c++) {
            u32 w = (__float_as_uint(he[2 * c]) >> 16) | (__float_as_uint(he[2 * c + 1]) & 0xffff0000u);
            *reinterpret_cast<u32*>(&s_he[j * 68 + 2 * c]) = w;
        }

        // semantic attention logits
        {
            float s0 = 0.f, s1 = 0.f, s2 = 0.f, s3 = 0.f;
            #pragma unroll 4
            for (int k = 0; k < 64; k++) {
                float vv = he[k];
                s0 += vv * LD<BF16>(p.Ws_, k * 4 + 0);
                s1 += vv * LD<BF16>(p.Ws_, k * 4 + 1);
                s2 += vv * LD<BF16>(p.Ws_, k * 4 + 2);
                s3 += vv * LD<BF16>(p.Ws_, k * 4 + 3);
            }
            float sub = (j == i) ? INFc : 0.f;
            s_sa[j * 4 + 0] = lrelu(s0 + LD<BF16>(p.bs_, 0)) - sub;
            s_sa[j * 4 + 1] = lrelu(s1 + LD<BF16>(p.bs_, 1)) - sub;
            s_sa[j * 4 + 2] = lrelu(s2 + LD<BF16>(p.bs_, 2)) - sub;
            s_sa[j * 4 + 3] = lrelu(s3 + LD<BF16>(p.bs_, 3)) - sub;
        }

        // coeff = silu(h_e @ Wc1 + bc1) @ Wc2 + bc2   (acc reused)
        #pragma unroll
        for (int o = 0; o < 64; o++) acc[o] = 0.f;
        #pragma unroll 2
        for (int k = 0; k < 64; k++) {
            float sk = he[k];
            #pragma unroll
            for (int o = 0; o < 64; o++) acc[o] += sk * LD<BF16>(p.Wc1, k * 64 + o);
        }
        #pragma unroll
        for (int o = 0; o < 64; o++) acc[o] = silu(acc[o] + LD<BF16>(p.bc1, o));

        float co[32];
        #pragma unroll
        for (int c = 0; c < 32; c++) co[c] = 0.f;
        #pragma unroll 2
        for (int k = 0; k < 64; k++) {
            float sk = acc[k];
            #pragma unroll
            for (int c = 0; c < 32; c++) co[c] += sk * LD<BF16>(p.Wc2, k * 32 + c);
        }
        #pragma unroll
        for (int c = 0; c < 16; c++) {
            float v0 = co[2 * c + 0] + LD<BF16>(p.bc2, 2 * c + 0);
            float v1 = co[2 * c + 1] + LD<BF16>(p.bc2, 2 * c + 1);
            *reinterpret_cast<u32*>(&s_co[j * 34 + 2 * c]) = (u32)f2bf(v0) | ((u32)f2bf(v1) << 16);
        }
    }
    __syncthreads();

    // ---------- phase 2: comb_sum / comb_norm / delta_v ----------
    if (tid < 96) {
        int c = tid & 31, k = tid >> 5;
        float a0 = 0.f, a1 = 0.f, a2 = 0.f, a3 = 0.f;
        for (int jj = 0; jj < 256; jj += 4) {
            a0 += bfr(s_co[(jj + 0) * 34 + c]) * s_xs[(jj + 0) * 4 + k];
            a1 += bfr(s_co[(jj + 1) * 34 + c]) * s_xs[(jj + 1) * 4 + k];
            a2 += bfr(s_co[(jj + 2) * 34 + c]) * s_xs[(jj + 2) * 4 + k];
            a3 += bfr(s_co[(jj + 3) * 34 + c]) * s_xs[(jj + 3) * 4 + k];
        }
        s_comb[c * 4 + k] = (a0 + a1) + (a2 + a3);
    }
    __syncthreads();
    if (tid < 32) {
        float x0 = s_comb[tid * 4 + 0], x1 = s_comb[tid * 4 + 1], x2 = s_comb[tid * 4 + 2];
        s_cn[tid] = x0 * x0 + x1 * x1 + x2 * x2;
    }
    if (tid >= 32 && tid < 35) {
        int k = tid - 32;
        float a = 0.f;
        #pragma unroll 8
        for (int c = 0; c < 32; c++) a += s_comb[c * 4 + k];
        s_dv[k] = a * (1.0f / (256.f * 32.f));
    }
    __syncthreads();

    // ---------- phase 3: the three j-softmaxes ----------
    {
        float nj = s_xs[j * 4 + 3];
        float pen = (j == i) ? INFc : 0.f;
        float ge[4] = { s_misc[4], s_misc[5], s_misc[6], s_misc[7] };
        float el[4], slq[4], r[4], ae[4], as_[4], pp[4];
        #pragma unroll
        for (int u = 0; u < 4; u++) el[u] = -(nj + pen) * ge[u];
        #pragma unroll
        for (int u = 0; u < 4; u++) slq[u] = s_sa[j * 4 + u];

        #pragma unroll
        for (int u = 0; u < 4; u++) r[u] = el[u];
        blk_reduce4(r, true, s_scr, tid);
        #pragma unroll
        for (int u = 0; u < 4; u++) ae[u] = __expf(el[u] - r[u]);
        #pragma unroll
        for (int u = 0; u < 4; u++) r[u] = ae[u];
        blk_reduce4(r, false, s_scr, tid);
        #pragma unroll
        for (int u = 0; u < 4; u++) ae[u] *= frcp(r[u]);

        #pragma unroll
        for (int u = 0; u < 4; u++) r[u] = slq[u];
        blk_reduce4(r, true, s_scr, tid);
        #pragma unroll
        for (int u = 0; u < 4; u++) as_[u] = __expf(slq[u] - r[u]);
        #pragma unroll
        for (int u = 0; u < 4; u++) r[u] = as_[u];
        blk_reduce4(r, false, s_scr, tid);
        #pragma unroll
        for (int u = 0; u < 4; u++) as_[u] *= frcp(r[u]);

        #pragma unroll
        for (int u = 0; u < 4; u++) pp[u] = ae[u] * as_[u];
        #pragma unroll
        for (int u = 0; u < 4; u++) r[u] = pp[u];
        blk_reduce4(r, true, s_scr, tid);
        #pragma unroll
        for (int u = 0; u < 4; u++) pp[u] = __expf(pp[u] - r[u]);
        #pragma unroll
        for (int u = 0; u < 4; u++) r[u] = pp[u];
        blk_reduce4(r, false, s_scr, tid);
        #pragma unroll
        for (int u = 0; u < 4; u++) s_sa[j * 4 + u] = pp[u] * frcp(r[u]);
    }
    __syncthreads();

    // ---------- phase 4: h_e aggregation + h_comb ----------
    {
        int hh2 = tid >> 2, nh = tid & 3;
        float a0 = 0.f, a1 = 0.f, a2 = 0.f, a3 = 0.f;
        for (int jj = 0; jj < 256; jj += 4) {
            a0 += bfr(s_he[(jj + 0) * 68 + hh2]) * s_sa[(jj + 0) * 4 + nh];
            a1 += bfr(s_he[(jj + 1) * 68 + hh2]) * s_sa[(jj + 1) * 4 + nh];
            a2 += bfr(s_he[(jj + 2) * 68 + hh2]) * s_sa[(jj + 2) * 4 + nh];
            a3 += bfr(s_he[(jj + 3) * 68 + hh2]) * s_sa[(jj + 3) * 4 + nh];
        }
        s_heagg[tid] = (a0 + a1) + (a2 + a3);   // index = h*4 + nh
    }
    if (tid < 64) {
        float a = LD<BF16>(p.bp1, tid);
        #pragma unroll 4
        for (int c = 0; c < 32; c++) a += s_cn[c] * LD<BF16>(p.Wp1, c * 64 + tid);
        s_t1[tid] = silu(a);
    }
    __syncthreads();
    if (tid < 64) {
        float a = LD<BF16>(p.bp2, tid);
        #pragma unroll 4
        for (int k = 0; k < 64; k++) a += s_t1[k] * LD<BF16>(p.Wp2, k * 64 + tid);
        s_hcomb[tid] = a;
    }
    __syncthreads();

    // ---------- phase 5: node MLP + residual; velocity / coordinates ----------
    float* s_part = s_xs;   // s_xs dead after phase 3
    {
        int qq = tid >> 6, o = tid & 63;
        int k0 = qq * 96;
        float a = 0.f;
        for (int k2 = k0; k2 < k0 + 96; k2++) {
            float inv;
            if (k2 < 64)       inv = s_rows[3 * 64 + k2];
            else if (k2 < 320) inv = s_heagg[k2 - 64];
            else               inv = s_hcomb[k2 - 320];
            a += inv * LD<BF16>(p.Wn1, k2 * 64 + o);
        }
        s_part[qq * 64 + o] = a;
    }
    __syncthreads();
    if (tid < 64) {
        float a = LD<BF16>(p.bn1, tid) + (s_part[tid] + s_part[64 + tid]) + (s_part[128 + tid] + s_part[192 + tid]);
        s_t1[tid] = silu(a);
    }
    __syncthreads();
    if (tid < 64) {
        float a = LD<BF16>(p.bn2, tid);
        #pragma unroll 4
        for (int k = 0; k < 64; k++) a += s_t1[k] * LD<BF16>(p.Wn2, k * 64 + tid);
        ST<BF16>(p.out, node * 64 + tid, s_rows[3 * 64 + tid] + a);           // h out
    } else if (tid < 67) {
        int k = tid - 64;
        float vn = s_dv[k] + s_misc[3] * LD<BF16>(p.v, node * 3 + k);
        float xn = LD<BF16>(p.x, node * 3 + k) + vn;
        ST<BF16>(p.out, 65536 + node * 3 + k, xn);                            // x out
        ST<BF16>(p.out, 68608 + node * 3 + k, vn);                            // v out
    }
}

extern "C" void kernel_launch(void* const* d_in, const int* in_sizes, int n_in,
                              void* d_out, int out_size, void* d_ws, size_t ws_size,
                              hipStream_t stream) {
    (void)in_sizes; (void)n_in; (void)out_size; (void)ws_size;
    u32* flag = (u32*)d_ws;
    hipLaunchKernelGGL(sniff_kernel, dim3(1), dim3(64), 0, stream, d_in[0], flag);

    Ptrs p;
    p.h   = d_in[0];  p.x   = d_in[1];  p.v   = d_in[2];
    p.We1 = d_in[3];  p.be1 = d_in[4];  p.We2 = d_in[5];  p.be2 = d_in[6];
    p.Wc1 = d_in[7];  p.bc1 = d_in[8];  p.Wc2 = d_in[9];  p.bc2 = d_in[10];
    p.Wp1 = d_in[11]; p.bp1 = d_in[12]; p.Wp2 = d_in[13]; p.bp2 = d_in[14];
    p.Ws_ = d_in[15]; p.bs_ = d_in[16];
    p.Wn1 = d_in[17]; p.bn1 = d_in[18]; p.Wn2 = d_in[19]; p.bn2 = d_in[20];
    p.Wv1 = d_in[21]; p.bv1 = d_in[22]; p.Wv2 = d_in[23]; p.lg  = d_in[24];
    p.out = d_out;
    p.flag = flag;

    hipLaunchKernelGGL(sake_all<1>, dim3(4 * 256), dim3(256), 0, stream, p);
    hipLaunchKernelGGL(sake_all<0>, dim3(4 * 256), dim3(256), 0, stream, p);
}

// Round 4
// 123.468 us; speedup vs baseline: 3.2444x; 3.2444x over previous
//
#include <hip/hip_runtime.h>

typedef unsigned short u16;
typedef unsigned int   u32;
typedef __attribute__((ext_vector_type(8))) short bf16x8;
typedef __attribute__((ext_vector_type(4))) float f32x4;

#define EPSc 1e-5f
#define INFc 1e5f

// ---------------- ws byte offsets ----------------
#define O_LINJ 0         // f32[1024][64]
#define O_LINI 262144    // f32[1024][64]
#define O_VSC  524288    // f32[1024]
#define O_WE2F 528384    // u16[8][64][8]   fragment-order We2
#define O_WC1F 536576    // u16[8][64][8]
#define O_WC2F 544768    // u16[4][64][8]
#define O_FLAG 548864    // u32

struct Ptrs {
    const void *h, *x, *v;
    const void *We1, *be1, *We2, *be2;
    const void *Wc1, *bc1, *Wc2, *bc2;
    const void *Wp1, *bp1, *Wp2, *bp2;
    const void *Ws_, *bs_;
    const void *Wn1, *bn1, *Wn2, *bn2;
    const void *Wv1, *bv1, *Wv2, *lg;
    const float *linj, *lini, *vsc;
    const u16 *we2f, *wc1f, *wc2f;
    const u32 *flag;
    void *out;
};

__device__ __forceinline__ float bfr(u16 u) { return __uint_as_float(((u32)u) << 16); }
__device__ __forceinline__ u16 f2bf(float f) {
    u32 u = __float_as_uint(f);
    u = u + 0x7fffu + ((u >> 16) & 1u);
    return (u16)(u >> 16);
}
__device__ __forceinline__ u32 packbf2(float lo, float hi) {
    return (u32)f2bf(lo) | ((u32)f2bf(hi) << 16);
}
__device__ __forceinline__ float frcp(float x) { return __builtin_amdgcn_rcpf(x); }
__device__ __forceinline__ float silu(float x) { return x * frcp(1.f + __expf(-x)); }
__device__ __forceinline__ float lrelu(float x) { return x > 0.f ? x : 0.2f * x; }

template<int BF16>
__device__ __forceinline__ float LD(const void* p, int i) {
    if constexpr (BF16) return bfr(((const u16*)p)[i]);
    else                return ((const float*)p)[i];
}
template<int BF16>
__device__ __forceinline__ u16 ENC(const void* p, int i) {
    if constexpr (BF16) return ((const u16*)p)[i];
    else                return f2bf(((const float*)p)[i]);
}
template<int BF16>
__device__ __forceinline__ void ST(void* p, int i, float v) {
    if constexpr (BF16) ((u16*)p)[i] = f2bf(v);
    else                ((float*)p)[i] = v;
}

// ---------------- dtype sniffer (worked in r3) ----------------
__global__ void sniff_kernel(const void* h, u32* flag) {
    if (threadIdx.x == 0) {
        const u16* ph = (const u16*)h;
        int cnt = 0;
        for (int k = 0; k < 256; k++) {
            float v = bfr(ph[k]);
            float a = fabsf(v);
            if (v == 0.f || (a > 1e-6f && a < 1024.f)) cnt++;
        }
        flag[0] = (cnt >= 224) ? 1u : 0u;
    }
}

// ---------------- prep: B-fragments in lane order ----------------
// frag idx = ((nt*2+ks)*64 + lane)*8 + e ; element = W[ks*32+(lane>>4)*8+e][nt*16+(lane&15)]
template<int BF16>
__global__ void prep_frags(const void* We2, const void* Wc1, const void* Wc2,
                           u16* d2, u16* d1, u16* dc, const u32* flag) {
    if ((flag[0] != 0u) != (BF16 != 0)) return;
    int t = threadIdx.x;
    for (int idx = t; idx < 4096; idx += 256) {
        int e = idx & 7, l = (idx >> 3) & 63, ks = (idx >> 9) & 1, nt = idx >> 10;
        int k = ks * 32 + (l >> 4) * 8 + e, n = nt * 16 + (l & 15);
        d2[idx] = ENC<BF16>(We2, k * 64 + n);
        d1[idx] = ENC<BF16>(Wc1, k * 64 + n);
    }
    for (int idx = t; idx < 2048; idx += 256) {
        int e = idx & 7, l = (idx >> 3) & 63, ks = (idx >> 9) & 1, nt = idx >> 10;
        int k = ks * 32 + (l >> 4) * 8 + e, n = nt * 16 + (l & 15);
        dc[idx] = ENC<BF16>(Wc2, k * 32 + n);
    }
}

// ---------------- prep: per-node lin_j, lin_i, vscale ----------------
template<int BF16>
__global__ __launch_bounds__(64) void prep_nodes(
    const void* h, const void* We1, const void* Wv1, const void* bv1,
    const void* Wv2, float* linj, float* lini, float* vsc, const u32* flag) {
    if ((flag[0] != 0u) != (BF16 != 0)) return;
    int n = blockIdx.x, t = threadIdx.x;
    __shared__ float hrow[64];
    hrow[t] = LD<BF16>(h, n * 64 + t);
    __syncthreads();
    float a0 = 0.f, a1 = 0.f, a2 = 0.f;
    #pragma unroll 2
    for (int k = 0; k < 64; k++) {
        float hv = hrow[k];
        a0 += hv * LD<BF16>(We1, k * 64 + t);
        a1 += hv * LD<BF16>(We1, (64 + k) * 64 + t);
        a2 += hv * LD<BF16>(Wv1, k * 64 + t);
    }
    linj[n * 64 + t] = a0;
    lini[n * 64 + t] = a1;
    float pv = silu(a2 + LD<BF16>(bv1, t)) * LD<BF16>(Wv2, t);
    #pragma unroll
    for (int o = 32; o; o >>= 1) pv += __shfl_down(pv, o);
    if (t == 0) vsc[n] = pv;
}

// block reduction over 256 threads for 4 values
__device__ __forceinline__ void blk_reduce4(float v[4], bool domax, float* scr, int tid) {
    #pragma unroll
    for (int s2 = 32; s2; s2 >>= 1) {
        #pragma unroll
        for (int u = 0; u < 4; u++) {
            float o = __shfl_xor(v[u], s2);
            v[u] = domax ? fmaxf(v[u], o) : (v[u] + o);
        }
    }
    __syncthreads();
    if ((tid & 63) == 0) {
        int w = tid >> 6;
        #pragma unroll
        for (int u = 0; u < 4; u++) scr[w * 4 + u] = v[u];
    }
    __syncthreads();
    #pragma unroll
    for (int u = 0; u < 4; u++) {
        float a = scr[0 + u], b = scr[4 + u], c = scr[8 + u], d = scr[12 + u];
        v[u] = domax ? fmaxf(fmaxf(a, b), fmaxf(c, d)) : ((a + b) + (c + d));
    }
}

// ---------------- main fused kernel: one block per (b,i) ----------------
template<int BF16>
__global__ __launch_bounds__(256) void sake_all(Ptrs p) {
    if ((p.flag[0] != 0u) != (BF16 != 0)) return;

    const int node = blockIdx.x;
    const int i = node & 255;
    const int b = node >> 8;
    const int tid = threadIdx.x;
    const int j = tid;
    const int lane = tid & 63, wv = tid >> 6;
    const int l15 = lane & 15, l4 = lane >> 4;

    // LDS: 58,608 B total -> 2 blocks/CU
    __shared__ alignas(16) u16 s_A[256 * 72];     // spre -> h_e (bf16, stride 72)
    __shared__ alignas(16) u16 s_wsq[4 * 16 * 72];// per-wave c1 scratch
    __shared__ alignas(16) float s_xs[256 * 4];   // xs0,xs1,xs2,nrm ; s_part alias later
    __shared__ float s_sa[256 * 4];               // logits -> final att
    __shared__ float s_rows[4 * 64];              // we1last | be1 | lin_i | h_i
    __shared__ float s_combw[4 * 32 * 3];
    __shared__ float s_cn[32];
    __shared__ float s_dv[4];
    __shared__ float s_heagg[256];
    __shared__ float s_t1[64];
    __shared__ float s_hcomb[64];
    __shared__ float s_scr[16];
    __shared__ float s_misc[8];                   // x_i | vsc | exp(lg)

    // early: issue We2 fragment loads (coalesced dwordx4, L2-broadcast)
    bf16x8 bw2[2][4];
    #pragma unroll
    for (int n = 0; n < 4; n++)
        #pragma unroll
        for (int ks = 0; ks < 2; ks++)
            bw2[ks][n] = *(const bf16x8*)(p.we2f + ((n * 2 + ks) * 64 + lane) * 8);
    float be2v[4];
    #pragma unroll
    for (int n = 0; n < 4; n++) be2v[n] = LD<BF16>(p.be2, n * 16 + l15);

    // ---------- P0: stage ----------
    if (tid < 64) {
        s_rows[0 * 64 + tid] = LD<BF16>(p.We1, 128 * 64 + tid);
        s_rows[1 * 64 + tid] = LD<BF16>(p.be1, tid);
        s_rows[2 * 64 + tid] = p.lini[node * 64 + tid];
        s_rows[3 * 64 + tid] = LD<BF16>(p.h, node * 64 + tid);
    } else if (tid < 67) {
        s_misc[tid - 64] = LD<BF16>(p.x, node * 3 + (tid - 64));
    } else if (tid == 67) {
        s_misc[3] = p.vsc[node];
    } else if (tid < 72) {
        s_misc[4 + (tid - 68)] = __expf(LD<BF16>(p.lg, tid - 68));
    }
    __syncthreads();

    // ---------- P1: xs + spre row (bf16 into s_A) ----------
    {
        float d0 = LD<BF16>(p.x, (b * 256 + j) * 3 + 0) - s_misc[0];
        float d1 = LD<BF16>(p.x, (b * 256 + j) * 3 + 1) - s_misc[1];
        float d2 = LD<BF16>(p.x, (b * 256 + j) * 3 + 2) - s_misc[2];
        float nrm = sqrtf(d0 * d0 + d1 * d1 + d2 * d2 + EPSc);
        float den = nrm + EPSc;
        float invd = frcp(den * den);
        s_xs[j * 4 + 0] = d0 * invd;
        s_xs[j * 4 + 1] = d1 * invd;
        s_xs[j * 4 + 2] = d2 * invd;
        s_xs[j * 4 + 3] = nrm;

        const f32x4* lj = (const f32x4*)(p.linj + (b * 256 + j) * 64);
        #pragma unroll
        for (int c = 0; c < 8; c++) {
            f32x4 a = lj[2 * c], bq = lj[2 * c + 1];
            float s[8];
            #pragma unroll
            for (int e = 0; e < 4; e++) {
                int o = c * 8 + e;
                s[e] = silu(a[e] + s_rows[128 + o] + nrm * s_rows[o] + s_rows[64 + o]);
            }
            #pragma unroll
            for (int e = 0; e < 4; e++) {
                int o = c * 8 + 4 + e;
                s[4 + e] = silu(bq[e] + s_rows[128 + o] + nrm * s_rows[o] + s_rows[64 + o]);
            }
            uint4 w;
            w.x = packbf2(s[0], s[1]); w.y = packbf2(s[2], s[3]);
            w.z = packbf2(s[4], s[5]); w.w = packbf2(s[6], s[7]);
            *(uint4*)(&s_A[j * 72 + c * 8]) = w;
        }
    }
    __syncthreads();

    // ---------- P2: GEMM1  he = silu(spre @ We2 + be2) ----------
    f32x4 acc[4][4] = {};
    #pragma unroll
    for (int mt = 0; mt < 4; mt++) {
        int row = (wv * 4 + mt) * 16 + l15;
        #pragma unroll
        for (int ks = 0; ks < 2; ks++) {
            bf16x8 a = *(const bf16x8*)(&s_A[row * 72 + ks * 32 + l4 * 8]);
            #pragma unroll
            for (int n = 0; n < 4; n++)
                acc[mt][n] = __builtin_amdgcn_mfma_f32_16x16x32_bf16(a, bw2[ks][n], acc[mt][n], 0, 0, 0);
        }
    }
    __syncthreads();          // all spre reads done
    // writeback he over spre
    #pragma unroll
    for (int mt = 0; mt < 4; mt++)
        #pragma unroll
        for (int n = 0; n < 4; n++)
            #pragma unroll
            for (int q = 0; q < 4; q++) {
                int row = (wv * 4 + mt) * 16 + l4 * 4 + q;
                s_A[row * 72 + n * 16 + l15] = f2bf(silu(acc[mt][n][q] + be2v[n]));
            }
    __syncthreads();

    // ---------- P4: semantic logits (thread j reads its he row) ----------
    {
        float he[64];
        #pragma unroll
        for (int c = 0; c < 8; c++) {
            bf16x8 w = *(const bf16x8*)(&s_A[j * 72 + c * 8]);
            #pragma unroll
            for (int e = 0; e < 8; e++) he[c * 8 + e] = bfr((u16)w[e]);
        }
        float s0 = 0.f, s1 = 0.f, s2 = 0.f, s3 = 0.f;
        #pragma unroll 4
        for (int k = 0; k < 64; k++) {
            float vv = he[k];
            s0 += vv * LD<BF16>(p.Ws_, k * 4 + 0);
            s1 += vv * LD<BF16>(p.Ws_, k * 4 + 1);
            s2 += vv * LD<BF16>(p.Ws_, k * 4 + 2);
            s3 += vv * LD<BF16>(p.Ws_, k * 4 + 3);
        }
        float sub = (j == i) ? INFc : 0.f;
        s_sa[j * 4 + 0] = lrelu(s0 + LD<BF16>(p.bs_, 0)) - sub;
        s_sa[j * 4 + 1] = lrelu(s1 + LD<BF16>(p.bs_, 1)) - sub;
        s_sa[j * 4 + 2] = lrelu(s2 + LD<BF16>(p.bs_, 2)) - sub;
        s_sa[j * 4 + 3] = lrelu(s3 + LD<BF16>(p.bs_, 3)) - sub;
    }

    // ---------- P5: GEMM2+3 per wave; comb from D-fragments ----------
    {
        bf16x8 bw3[2][4], bw4[2][2];
        #pragma unroll
        for (int n = 0; n < 4; n++)
            #pragma unroll
            for (int ks = 0; ks < 2; ks++)
                bw3[ks][n] = *(const bf16x8*)(p.wc1f + ((n * 2 + ks) * 64 + lane) * 8);
        #pragma unroll
        for (int n = 0; n < 2; n++)
            #pragma unroll
            for (int ks = 0; ks < 2; ks++)
                bw4[ks][n] = *(const bf16x8*)(p.wc2f + ((n * 2 + ks) * 64 + lane) * 8);
        float bc1v[4], bc2v[2];
        #pragma unroll
        for (int n = 0; n < 4; n++) bc1v[n] = LD<BF16>(p.bc1, n * 16 + l15);
        #pragma unroll
        for (int n = 0; n < 2; n++) bc2v[n] = LD<BF16>(p.bc2, n * 16 + l15);

        u16* myws = s_wsq + wv * (16 * 72);
        float cmb[2][3] = {};
        #pragma unroll 1
        for (int mt = 0; mt < 4; mt++) {
            f32x4 c1[4] = {};
            #pragma unroll
            for (int ks = 0; ks < 2; ks++) {
                bf16x8 a = *(const bf16x8*)(&s_A[((wv * 4 + mt) * 16 + l15) * 72 + ks * 32 + l4 * 8]);
                #pragma unroll
                for (int n = 0; n < 4; n++)
                    c1[n] = __builtin_amdgcn_mfma_f32_16x16x32_bf16(a, bw3[ks][n], c1[n], 0, 0, 0);
            }
            #pragma unroll
            for (int n = 0; n < 4; n++)
                #pragma unroll
                for (int q = 0; q < 4; q++)
                    myws[(l4 * 4 + q) * 72 + n * 16 + l15] = f2bf(silu(c1[n][q] + bc1v[n]));
            // GEMM3 on this 16-row tile (per-wave scratch, no block barrier needed)
            f32x4 co[2] = {};
            #pragma unroll
            for (int ks = 0; ks < 2; ks++) {
                bf16x8 a2 = *(const bf16x8*)(&myws[l15 * 72 + ks * 32 + l4 * 8]);
                #pragma unroll
                for (int n = 0; n < 2; n++)
                    co[n] = __builtin_amdgcn_mfma_f32_16x16x32_bf16(a2, bw4[ks][n], co[n], 0, 0, 0);
            }
            #pragma unroll
            for (int q = 0; q < 4; q++) {
                int r = (wv * 4 + mt) * 16 + l4 * 4 + q;
                f32x4 xs = *(const f32x4*)(&s_xs[r * 4]);
                #pragma unroll
                for (int n = 0; n < 2; n++) {
                    float c = co[n][q] + bc2v[n];
                    cmb[n][0] += c * xs[0];
                    cmb[n][1] += c * xs[1];
                    cmb[n][2] += c * xs[2];
                }
            }
        }
        #pragma unroll
        for (int n = 0; n < 2; n++)
            #pragma unroll
            for (int k = 0; k < 3; k++) {
                float v = cmb[n][k];
                v += __shfl_xor(v, 16);
                v += __shfl_xor(v, 32);
                cmb[n][k] = v;
            }
        if (l4 == 0) {
            #pragma unroll
            for (int n = 0; n < 2; n++)
                #pragma unroll
                for (int k = 0; k < 3; k++)
                    s_combw[(wv * 32 + n * 16 + l15) * 3 + k] = cmb[n][k];
        }
    }
    __syncthreads();

    // ---------- P6: comb_norm + delta_v ----------
    if (tid < 32) {
        float c0 = 0.f, c1 = 0.f, c2 = 0.f;
        #pragma unroll
        for (int w = 0; w < 4; w++) {
            c0 += s_combw[(w * 32 + tid) * 3 + 0];
            c1 += s_combw[(w * 32 + tid) * 3 + 1];
            c2 += s_combw[(w * 32 + tid) * 3 + 2];
        }
        s_cn[tid] = c0 * c0 + c1 * c1 + c2 * c2;
    } else if (tid < 35) {
        int k = tid - 32;
        float a = 0.f;
        for (int w = 0; w < 4; w++)
            #pragma unroll 8
            for (int c = 0; c < 32; c++) a += s_combw[(w * 32 + c) * 3 + k];
        s_dv[k] = a * (1.0f / 8192.f);
    }
    __syncthreads();

    // ---------- P7: three j-softmaxes ----------
    {
        float nj = s_xs[j * 4 + 3];
        float pen = (j == i) ? INFc : 0.f;
        float ge[4] = { s_misc[4], s_misc[5], s_misc[6], s_misc[7] };
        float el[4], slq[4], r[4], ae[4], as_[4], pp[4];
        #pragma unroll
        for (int u = 0; u < 4; u++) el[u] = -(nj + pen) * ge[u];
        #pragma unroll
        for (int u = 0; u < 4; u++) slq[u] = s_sa[j * 4 + u];

        #pragma unroll
        for (int u = 0; u < 4; u++) r[u] = el[u];
        blk_reduce4(r, true, s_scr, tid);
        #pragma unroll
        for (int u = 0; u < 4; u++) ae[u] = __expf(el[u] - r[u]);
        #pragma unroll
        for (int u = 0; u < 4; u++) r[u] = ae[u];
        blk_reduce4(r, false, s_scr, tid);
        #pragma unroll
        for (int u = 0; u < 4; u++) ae[u] *= frcp(r[u]);

        #pragma unroll
        for (int u = 0; u < 4; u++) r[u] = slq[u];
        blk_reduce4(r, true, s_scr, tid);
        #pragma unroll
        for (int u = 0; u < 4; u++) as_[u] = __expf(slq[u] - r[u]);
        #pragma unroll
        for (int u = 0; u < 4; u++) r[u] = as_[u];
        blk_reduce4(r, false, s_scr, tid);
        #pragma unroll
        for (int u = 0; u < 4; u++) as_[u] *= frcp(r[u]);

        #pragma unroll
        for (int u = 0; u < 4; u++) pp[u] = ae[u] * as_[u];
        #pragma unroll
        for (int u = 0; u < 4; u++) r[u] = pp[u];
        blk_reduce4(r, true, s_scr, tid);
        #pragma unroll
        for (int u = 0; u < 4; u++) pp[u] = __expf(pp[u] - r[u]);
        #pragma unroll
        for (int u = 0; u < 4; u++) r[u] = pp[u];
        blk_reduce4(r, false, s_scr, tid);
        #pragma unroll
        for (int u = 0; u < 4; u++) s_sa[j * 4 + u] = pp[u] * frcp(r[u]);
    }
    __syncthreads();

    // ---------- P8: h_e aggregation + h_comb part 1 ----------
    {
        int hh2 = tid >> 2, nh = tid & 3;
        float a0 = 0.f, a1 = 0.f, a2 = 0.f, a3 = 0.f;
        for (int jj = 0; jj < 256; jj += 4) {
            a0 += bfr(s_A[(jj + 0) * 72 + hh2]) * s_sa[(jj + 0) * 4 + nh];
            a1 += bfr(s_A[(jj + 1) * 72 + hh2]) * s_sa[(jj + 1) * 4 + nh];
            a2 += bfr(s_A[(jj + 2) * 72 + hh2]) * s_sa[(jj + 2) * 4 + nh];
            a3 += bfr(s_A[(jj + 3) * 72 + hh2]) * s_sa[(jj + 3) * 4 + nh];
        }
        s_heagg[tid] = (a0 + a1) + (a2 + a3);
    }
    if (tid < 64) {
        float a = LD<BF16>(p.bp1, tid);
        #pragma unroll 4
        for (int c = 0; c < 32; c++) a += s_cn[c] * LD<BF16>(p.Wp1, c * 64 + tid);
        s_t1[tid] = silu(a);
    }
    __syncthreads();
    if (tid < 64) {
        float a = LD<BF16>(p.bp2, tid);
        #pragma unroll 4
        for (int k = 0; k < 64; k++) a += s_t1[k] * LD<BF16>(p.Wp2, k * 64 + tid);
        s_hcomb[tid] = a;
    }
    __syncthreads();

    // ---------- P10: node MLP + residual; velocity / coordinates ----------
    float* s_part = s_xs;
    {
        int qq = tid >> 6, o = tid & 63;
        int k0 = qq * 96;
        float a = 0.f;
        for (int k2 = k0; k2 < k0 + 96; k2++) {
            float inv;
            if (k2 < 64)       inv = s_rows[3 * 64 + k2];
            else if (k2 < 320) inv = s_heagg[k2 - 64];
            else               inv = s_hcomb[k2 - 320];
            a += inv * LD<BF16>(p.Wn1, k2 * 64 + o);
        }
        s_part[qq * 64 + o] = a;
    }
    __syncthreads();
    if (tid < 64) {
        float a = LD<BF16>(p.bn1, tid) + (s_part[tid] + s_part[64 + tid]) + (s_part[128 + tid] + s_part[192 + tid]);
        s_t1[tid] = silu(a);
    }
    __syncthreads();
    if (tid < 64) {
        float a = LD<BF16>(p.bn2, tid);
        #pragma unroll 4
        for (int k = 0; k < 64; k++) a += s_t1[k] * LD<BF16>(p.Wn2, k * 64 + tid);
        ST<BF16>(p.out, node * 64 + tid, s_rows[3 * 64 + tid] + a);
    } else if (tid < 67) {
        int k = tid - 64;
        float vn = s_dv[k] + s_misc[3] * LD<BF16>(p.v, node * 3 + k);
        float xn = LD<BF16>(p.x, node * 3 + k) + vn;
        ST<BF16>(p.out, 65536 + node * 3 + k, xn);
        ST<BF16>(p.out, 68608 + node * 3 + k, vn);
    }
}

extern "C" void kernel_launch(void* const* d_in, const int* in_sizes, int n_in,
                              void* d_out, int out_size, void* d_ws, size_t ws_size,
                              hipStream_t stream) {
    (void)in_sizes; (void)n_in; (void)out_size; (void)ws_size;
    char* ws = (char*)d_ws;
    float* linj = (float*)(ws + O_LINJ);
    float* lini = (float*)(ws + O_LINI);
    float* vsc  = (float*)(ws + O_VSC);
    u16* we2f = (u16*)(ws + O_WE2F);
    u16* wc1f = (u16*)(ws + O_WC1F);
    u16* wc2f = (u16*)(ws + O_WC2F);
    u32* flag = (u32*)(ws + O_FLAG);

    hipLaunchKernelGGL(sniff_kernel, dim3(1), dim3(64), 0, stream, d_in[0], flag);

    hipLaunchKernelGGL(prep_frags<1>, dim3(1), dim3(256), 0, stream,
                       d_in[5], d_in[7], d_in[9], we2f, wc1f, wc2f, flag);
    hipLaunchKernelGGL(prep_frags<0>, dim3(1), dim3(256), 0, stream,
                       d_in[5], d_in[7], d_in[9], we2f, wc1f, wc2f, flag);
    hipLaunchKernelGGL(prep_nodes<1>, dim3(1024), dim3(64), 0, stream,
                       d_in[0], d_in[3], d_in[21], d_in[22], d_in[23], linj, lini, vsc, flag);
    hipLaunchKernelGGL(prep_nodes<0>, dim3(1024), dim3(64), 0, stream,
                       d_in[0], d_in[3], d_in[21], d_in[22], d_in[23], linj, lini, vsc, flag);

    Ptrs p;
    p.h   = d_in[0];  p.x   = d_in[1];  p.v   = d_in[2];
    p.We1 = d_in[3];  p.be1 = d_in[4];  p.We2 = d_in[5];  p.be2 = d_in[6];
    p.Wc1 = d_in[7];  p.bc1 = d_in[8];  p.Wc2 = d_in[9];  p.bc2 = d_in[10];
    p.Wp1 = d_in[11]; p.bp1 = d_in[12]; p.Wp2 = d_in[13]; p.bp2 = d_in[14];
    p.Ws_ = d_in[15]; p.bs_ = d_in[16];
    p.Wn1 = d_in[17]; p.bn1 = d_in[18]; p.Wn2 = d_in[19]; p.bn2 = d_in[20];
    p.Wv1 = d_in[21]; p.bv1 = d_in[22]; p.Wv2 = d_in[23]; p.lg  = d_in[24];
    p.linj = linj; p.lini = lini; p.vsc = vsc;
    p.we2f = we2f; p.wc1f = wc1f; p.wc2f = wc2f;
    p.flag = flag;
    p.out = d_out;

    hipLaunchKernelGGL(sake_all<1>, dim3(1024), dim3(256), 0, stream, p);
    hipLaunchKernelGGL(sake_all<0>, dim3(1024), dim3(256), 0, stream, p);
}

// Round 5
// 74.034 us; speedup vs baseline: 5.4107x; 1.6677x over previous
//
#include <hip/hip_runtime.h>

typedef unsigned short u16;
typedef unsigned int   u32;
typedef __attribute__((ext_vector_type(8))) short bf16x8;
typedef __attribute__((ext_vector_type(4))) float f32x4;

#define EPSc 1e-5f
#define INFc 1e5f

// ---------------- ws byte offsets ----------------
#define O_LINJ 0         // f32[1024][64]
#define O_LINI 262144    // f32[1024][64]
#define O_VSC  524288    // f32[1024]
#define O_WE2F 528384    // u16[4*2*64*8]
#define O_WC1F 536576    // u16[5*2*64*8]  (tile n=4 = Ws | 0)
#define O_WC2F 546816    // u16[2*2*64*8]
#define O_FLAG 550912

struct Ptrs {
    const void *h, *x, *v;
    const void *We1, *be1, *be2;
    const void *bc1, *bc2;
    const void *Wp1, *bp1, *Wp2, *bp2;
    const void *bs_;
    const void *Wn1, *bn1, *Wn2, *bn2;
    const void *lg;
    const float *linj, *lini, *vsc;
    const u16 *we2f, *wc1f, *wc2f;
    const u32 *flag;
    void *out;
};

__device__ __forceinline__ float bfr(u16 u) { return __uint_as_float(((u32)u) << 16); }
__device__ __forceinline__ u16 f2bf(float f) {
    u32 u = __float_as_uint(f);
    u = u + 0x7fffu + ((u >> 16) & 1u);
    return (u16)(u >> 16);
}
__device__ __forceinline__ u32 packbf2(float lo, float hi) {
    return (u32)f2bf(lo) | ((u32)f2bf(hi) << 16);
}
__device__ __forceinline__ float frcp(float x) { return __builtin_amdgcn_rcpf(x); }
__device__ __forceinline__ float silu(float x) { return x * frcp(1.f + __expf(-x)); }
__device__ __forceinline__ float lrelu(float x) { return x > 0.f ? x : 0.2f * x; }

template<int BF16>
__device__ __forceinline__ float LD(const void* p, int i) {
    if constexpr (BF16) return bfr(((const u16*)p)[i]);
    else                return ((const float*)p)[i];
}
template<int BF16>
__device__ __forceinline__ void ST(void* p, int i, float v) {
    if constexpr (BF16) ((u16*)p)[i] = f2bf(v);
    else                ((float*)p)[i] = v;
}
__device__ __forceinline__ float LDr(const void* p, int i, bool bf) {
    return bf ? bfr(((const u16*)p)[i]) : ((const float*)p)[i];
}
__device__ __forceinline__ u16 ENCr(const void* p, int i, bool bf) {
    return bf ? ((const u16*)p)[i] : f2bf(((const float*)p)[i]);
}

// ---------------- dtype sniffer (proven r3/r4) ----------------
__global__ void sniff_kernel(const void* h, u32* flag) {
    if (threadIdx.x == 0) {
        const u16* ph = (const u16*)h;
        int cnt = 0;
        for (int k = 0; k < 256; k++) {
            float v = bfr(ph[k]);
            float a = fabsf(v);
            if (v == 0.f || (a > 1e-6f && a < 1024.f)) cnt++;
        }
        flag[0] = (cnt >= 224) ? 1u : 0u;
    }
}

// ---------------- merged prep: block0 = fragments, blocks 1..256 = 4 nodes each ----------------
__global__ __launch_bounds__(256) void prep_all(
    const void* h, const void* We1, const void* We2, const void* Wc1,
    const void* Wc2, const void* Ws_, const void* Wv1, const void* bv1,
    const void* Wv2,
    float* linj, float* lini, float* vsc,
    u16* we2f, u16* wc1f, u16* wc2f, const u32* flag) {
    const bool bf = (flag[0] != 0u);
    const int t = threadIdx.x;
    if (blockIdx.x == 0) {
        for (int idx = t; idx < 4096; idx += 256) {
            int e = idx & 7, l = (idx >> 3) & 63, ks = (idx >> 9) & 1, nt = idx >> 10;
            int k = ks * 32 + (l >> 4) * 8 + e, n = nt * 16 + (l & 15);
            we2f[idx] = ENCr(We2, k * 64 + n, bf);
        }
        for (int idx = t; idx < 5120; idx += 256) {
            int e = idx & 7, l = (idx >> 3) & 63, ks = (idx >> 9) & 1, nt = idx >> 10;
            int k = ks * 32 + (l >> 4) * 8 + e, c = l & 15;
            u16 v;
            if (nt < 4) v = ENCr(Wc1, k * 64 + nt * 16 + c, bf);
            else        v = (c < 4) ? ENCr(Ws_, k * 4 + c, bf) : (u16)0;
            wc1f[idx] = v;
        }
        for (int idx = t; idx < 2048; idx += 256) {
            int e = idx & 7, l = (idx >> 3) & 63, ks = (idx >> 9) & 1, nt = idx >> 10;
            int k = ks * 32 + (l >> 4) * 8 + e, n = nt * 16 + (l & 15);
            wc2f[idx] = ENCr(Wc2, k * 32 + n, bf);
        }
    } else {
        const int g = t >> 6, tt = t & 63;
        const int n = (blockIdx.x - 1) * 4 + g;
        __shared__ float hr[4][64];
        hr[g][tt] = LDr(h, n * 64 + tt, bf);
        __syncthreads();
        float a0 = 0.f, a1 = 0.f, a2 = 0.f;
        #pragma unroll 2
        for (int k = 0; k < 64; k++) {
            float hv = hr[g][k];
            a0 += hv * LDr(We1, k * 64 + tt, bf);
            a1 += hv * LDr(We1, (64 + k) * 64 + tt, bf);
            a2 += hv * LDr(Wv1, k * 64 + tt, bf);
        }
        linj[n * 64 + tt] = a0;
        lini[n * 64 + tt] = a1;
        float pv = silu(a2 + LDr(bv1, tt, bf)) * LDr(Wv2, tt, bf);
        #pragma unroll
        for (int o = 32; o; o >>= 1) pv += __shfl_down(pv, o);
        if (tt == 0) vsc[n] = pv;
    }
}

// N-channel block reduction over 256 threads (4 waves)
template<int N>
__device__ __forceinline__ void blk_red(float v[N], bool domax, float* scr, int tid) {
    #pragma unroll
    for (int s2 = 32; s2; s2 >>= 1)
        #pragma unroll
        for (int u = 0; u < N; u++) {
            float o = __shfl_xor(v[u], s2);
            v[u] = domax ? fmaxf(v[u], o) : (v[u] + o);
        }
    __syncthreads();
    if ((tid & 63) == 0) {
        int w = tid >> 6;
        #pragma unroll
        for (int u = 0; u < N; u++) scr[w * N + u] = v[u];
    }
    __syncthreads();
    #pragma unroll
    for (int u = 0; u < N; u++) {
        float a = scr[0 * N + u], b2 = scr[1 * N + u], c = scr[2 * N + u], d = scr[3 * N + u];
        v[u] = domax ? fmaxf(fmaxf(a, b2), fmaxf(c, d)) : ((a + b2) + (c + d));
    }
}

// ---------------- main fused kernel: one block per (b,i) ----------------
template<int BF16>
__global__ __launch_bounds__(256, 3) void sake_all(Ptrs p) {
    if ((p.flag[0] != 0u) != (BF16 != 0)) return;

    const int node = blockIdx.x;
    const int i = node & 255;
    const int b = node >> 8;
    const int tid = threadIdx.x;
    const int j = tid;
    const int lane = tid & 63, wv = tid >> 6;
    const int l15 = lane & 15, l4 = lane >> 4;

    // ---- LDS 53,680 B -> 3 blocks/CU ----
    __shared__ alignas(16) u16 s_A[256 * 72];     // spre/he [j][h] stride 72; later s_AT [64][272]
    __shared__ alignas(16) u16 s_wsq[4 * 16 * 72];// c1 tiles; later heagg|t1|hcomb
    __shared__ alignas(16) u16 s_xs[256 * 4];     // bf16 {xs0,xs1,xs2,nrm}; later s_part f32[256]
    __shared__ alignas(8)  u16 s_sa[256 * 4];     // bf16 semantic logits
    __shared__ alignas(16) u16 s_att[4 * 272];    // combw f32[384] alias -> attT bf16 [4][272]
    __shared__ float s_rows[4 * 64];              // we1last | be1 | lin_i | h_i
    __shared__ float s_cn[32];
    __shared__ float s_dv[4];
    __shared__ float s_scr[32];
    __shared__ float s_misc[8];                   // x_i | vsc | exp(lg)

    u16*   s_AT    = s_A;                          // [64][272]
    float* s_heagg = (float*)s_wsq;                // [256]
    float* s_t1    = (float*)((char*)s_wsq + 1024);// [64]
    float* s_hcomb = (float*)((char*)s_wsq + 1280);// [64]
    float* s_combw = (float*)s_att;                // [4][32][3]
    float* s_part  = (float*)s_xs;                 // [256]

    // early: We2 fragment loads (coalesced b128, L2-broadcast)
    bf16x8 bw2[2][4];
    #pragma unroll
    for (int n = 0; n < 4; n++)
        #pragma unroll
        for (int ks = 0; ks < 2; ks++)
            bw2[ks][n] = *(const bf16x8*)(p.we2f + ((n * 2 + ks) * 64 + lane) * 8);
    float be2v[4];
    #pragma unroll
    for (int n = 0; n < 4; n++) be2v[n] = LD<BF16>(p.be2, n * 16 + l15);

    // ---------- P0: stage ----------
    if (tid < 64) {
        s_rows[0 * 64 + tid] = LD<BF16>(p.We1, 128 * 64 + tid);
        s_rows[1 * 64 + tid] = LD<BF16>(p.be1, tid);
        s_rows[2 * 64 + tid] = p.lini[node * 64 + tid];
        s_rows[3 * 64 + tid] = LD<BF16>(p.h, node * 64 + tid);
    } else if (tid < 67) {
        s_misc[tid - 64] = LD<BF16>(p.x, node * 3 + (tid - 64));
    } else if (tid == 67) {
        s_misc[3] = p.vsc[node];
    } else if (tid < 72) {
        s_misc[4 + (tid - 68)] = __expf(LD<BF16>(p.lg, tid - 68));
    }
    __syncthreads();

    // ---------- P1: xs + spre ----------
    {
        float d0 = LD<BF16>(p.x, (b * 256 + j) * 3 + 0) - s_misc[0];
        float d1 = LD<BF16>(p.x, (b * 256 + j) * 3 + 1) - s_misc[1];
        float d2 = LD<BF16>(p.x, (b * 256 + j) * 3 + 2) - s_misc[2];
        float nrm = sqrtf(d0 * d0 + d1 * d1 + d2 * d2 + EPSc);
        float den = nrm + EPSc;
        float invd = frcp(den * den);
        uint2 xw;
        xw.x = packbf2(d0 * invd, d1 * invd);
        xw.y = packbf2(d2 * invd, nrm);
        *(uint2*)(&s_xs[j * 4]) = xw;

        const f32x4* lj = (const f32x4*)(p.linj + (b * 256 + j) * 64);
        #pragma unroll
        for (int c = 0; c < 8; c++) {
            f32x4 a = lj[2 * c], bq = lj[2 * c + 1];
            float s[8];
            #pragma unroll
            for (int e = 0; e < 4; e++) {
                int o = c * 8 + e;
                s[e] = silu(a[e] + s_rows[128 + o] + nrm * s_rows[o] + s_rows[64 + o]);
            }
            #pragma unroll
            for (int e = 0; e < 4; e++) {
                int o = c * 8 + 4 + e;
                s[4 + e] = silu(bq[e] + s_rows[128 + o] + nrm * s_rows[o] + s_rows[64 + o]);
            }
            uint4 w;
            w.x = packbf2(s[0], s[1]); w.y = packbf2(s[2], s[3]);
            w.z = packbf2(s[4], s[5]); w.w = packbf2(s[6], s[7]);
            *(uint4*)(&s_A[j * 72 + c * 8]) = w;
        }
    }
    __syncthreads();

    // ---------- GEMM1: he_pre = spre @ We2 ----------
    f32x4 acc[4][4] = {};
    #pragma unroll
    for (int mt = 0; mt < 4; mt++) {
        int row = (wv * 4 + mt) * 16 + l15;
        #pragma unroll
        for (int ks = 0; ks < 2; ks++) {
            bf16x8 a = *(const bf16x8*)(&s_A[row * 72 + ks * 32 + l4 * 8]);
            #pragma unroll
            for (int n = 0; n < 4; n++)
                acc[mt][n] = __builtin_amdgcn_mfma_f32_16x16x32_bf16(a, bw2[ks][n], acc[mt][n], 0, 0, 0);
        }
    }
    __syncthreads();
    // ---------- P2: he writeback (scalar u16, ~2-way) ----------
    #pragma unroll
    for (int mt = 0; mt < 4; mt++)
        #pragma unroll
        for (int n = 0; n < 4; n++)
            #pragma unroll
            for (int q = 0; q < 4; q++) {
                int row = (wv * 4 + mt) * 16 + l4 * 4 + q;
                s_A[row * 72 + n * 16 + l15] = f2bf(silu(acc[mt][n][q] + be2v[n]));
            }
    __syncthreads();

    // ---------- S4: GEMM2 (+logits tile) and GEMM3, cmb ----------
    {
        bf16x8 bw3[2][5], bw4[2][2];
        #pragma unroll
        for (int n = 0; n < 5; n++)
            #pragma unroll
            for (int ks = 0; ks < 2; ks++)
                bw3[ks][n] = *(const bf16x8*)(p.wc1f + ((n * 2 + ks) * 64 + lane) * 8);
        #pragma unroll
        for (int n = 0; n < 2; n++)
            #pragma unroll
            for (int ks = 0; ks < 2; ks++)
                bw4[ks][n] = *(const bf16x8*)(p.wc2f + ((n * 2 + ks) * 64 + lane) * 8);
        float bc1v[4], bc2v[2];
        #pragma unroll
        for (int n = 0; n < 4; n++) bc1v[n] = LD<BF16>(p.bc1, n * 16 + l15);
        #pragma unroll
        for (int n = 0; n < 2; n++) bc2v[n] = LD<BF16>(p.bc2, n * 16 + l15);
        float bsv = LD<BF16>(p.bs_, l15 & 3);

        u16* myws = s_wsq + wv * (16 * 72);
        float cmb[2][3] = {};
        #pragma unroll 1
        for (int mt = 0; mt < 4; mt++) {
            f32x4 c1x[5] = {};
            #pragma unroll
            for (int ks = 0; ks < 2; ks++) {
                bf16x8 a = *(const bf16x8*)(&s_A[((wv * 4 + mt) * 16 + l15) * 72 + ks * 32 + l4 * 8]);
                #pragma unroll
                for (int n = 0; n < 5; n++)
                    c1x[n] = __builtin_amdgcn_mfma_f32_16x16x32_bf16(a, bw3[ks][n], c1x[n], 0, 0, 0);
            }
            // c1 -> wsq (conflict-light scalar writes)
            #pragma unroll
            for (int n = 0; n < 4; n++)
                #pragma unroll
                for (int q = 0; q < 4; q++)
                    myws[(l4 * 4 + q) * 72 + n * 16 + l15] = f2bf(silu(c1x[n][q] + bc1v[n]));
            // semantic logits from tile n=4
            if (l15 < 4) {
                #pragma unroll
                for (int q = 0; q < 4; q++) {
                    int row = wv * 64 + mt * 16 + l4 * 4 + q;
                    float sub = (row == i) ? INFc : 0.f;
                    s_sa[row * 4 + l15] = f2bf(lrelu(c1x[4][q] + bsv) - sub);
                }
            }
            asm volatile("s_waitcnt lgkmcnt(0)" ::: "memory");
            __builtin_amdgcn_sched_barrier(0);
            // GEMM3 on this 16-row tile
            f32x4 co[2] = {};
            #pragma unroll
            for (int ks = 0; ks < 2; ks++) {
                bf16x8 a2 = *(const bf16x8*)(&myws[l15 * 72 + ks * 32 + l4 * 8]);
                #pragma unroll
                for (int n = 0; n < 2; n++)
                    co[n] = __builtin_amdgcn_mfma_f32_16x16x32_bf16(a2, bw4[ks][n], co[n], 0, 0, 0);
            }
            #pragma unroll
            for (int q = 0; q < 4; q++) {
                int r = wv * 64 + mt * 16 + l4 * 4 + q;
                uint2 xw = *(const uint2*)(&s_xs[r * 4]);
                float x0 = __uint_as_float(xw.x << 16);
                float x1 = __uint_as_float(xw.x & 0xffff0000u);
                float x2 = __uint_as_float(xw.y << 16);
                #pragma unroll
                for (int n = 0; n < 2; n++) {
                    float c = co[n][q] + bc2v[n];
                    cmb[n][0] += c * x0;
                    cmb[n][1] += c * x1;
                    cmb[n][2] += c * x2;
                }
            }
        }
        #pragma unroll
        for (int n = 0; n < 2; n++)
            #pragma unroll
            for (int k = 0; k < 3; k++) {
                float v = cmb[n][k];
                v += __shfl_xor(v, 16);
                v += __shfl_xor(v, 32);
                cmb[n][k] = v;
            }
        if (l4 == 0) {
            #pragma unroll
            for (int n = 0; n < 2; n++)
                #pragma unroll
                for (int k = 0; k < 3; k++)
                    s_combw[(wv * 32 + n * 16 + l15) * 3 + k] = cmb[n][k];
        }
    }
    __syncthreads();

    // ---------- S5: transpose-read he + P6 compute (regs) ----------
    uint4 her[8];
    #pragma unroll
    for (int c = 0; c < 8; c++) her[c] = *(const uint4*)(&s_A[j * 72 + c * 8]);
    float cnv = 0.f, dvv = 0.f;
    if (tid < 32) {
        float c0 = 0.f, c1 = 0.f, c2 = 0.f;
        #pragma unroll
        for (int w = 0; w < 4; w++) {
            c0 += s_combw[(w * 32 + tid) * 3 + 0];
            c1 += s_combw[(w * 32 + tid) * 3 + 1];
            c2 += s_combw[(w * 32 + tid) * 3 + 2];
        }
        cnv = c0 * c0 + c1 * c1 + c2 * c2;
    } else if (tid < 35) {
        int k = tid - 32;
        float a = 0.f;
        for (int w = 0; w < 4; w++)
            #pragma unroll 8
            for (int c = 0; c < 32; c++) a += s_combw[(w * 32 + c) * 3 + k];
        dvv = a * (1.0f / 8192.f);
    }
    __syncthreads();

    // ---------- S6: transpose-write s_AT[h][j] + store cn/dv ----------
    #pragma unroll
    for (int c = 0; c < 8; c++) {
        u32 d[4] = { her[c].x, her[c].y, her[c].z, her[c].w };
        #pragma unroll
        for (int dw = 0; dw < 4; dw++) {
            int h = c * 8 + dw * 2;
            s_AT[h * 272 + j]       = (u16)(d[dw] & 0xffffu);
            s_AT[(h + 1) * 272 + j] = (u16)(d[dw] >> 16);
        }
    }
    if (tid < 32) s_cn[tid] = cnv;
    else if (tid < 35) s_dv[tid - 32] = dvv;

    // ---------- P7: fused softmaxes ----------
    {
        float nrm = bfr(s_xs[j * 4 + 3]);
        float pen = (j == i) ? INFc : 0.f;
        float elb = -(nrm + pen);
        float sl[4];
        #pragma unroll
        for (int u = 0; u < 4; u++) sl[u] = bfr(s_sa[j * 4 + u]);
        float ge[4] = { s_misc[4], s_misc[5], s_misc[6], s_misc[7] };

        float r5[5] = { elb, sl[0], sl[1], sl[2], sl[3] };
        blk_red<5>(r5, true, s_scr, tid);

        float ae[4], as_[4];
        #pragma unroll
        for (int u = 0; u < 4; u++) ae[u] = __expf(ge[u] * (elb - r5[0]));
        #pragma unroll
        for (int u = 0; u < 4; u++) as_[u] = __expf(sl[u] - r5[1 + u]);

        float r8[8] = { ae[0], ae[1], ae[2], ae[3], as_[0], as_[1], as_[2], as_[3] };
        blk_red<8>(r8, false, s_scr, tid);

        float ep[4];
        #pragma unroll
        for (int u = 0; u < 4; u++)
            ep[u] = __expf(ae[u] * frcp(r8[u]) * as_[u] * frcp(r8[4 + u]));
        float r4v[4] = { ep[0], ep[1], ep[2], ep[3] };
        blk_red<4>(r4v, false, s_scr, tid);
        #pragma unroll
        for (int u = 0; u < 4; u++)
            s_att[u * 272 + j] = f2bf(ep[u] * frcp(r4v[u]));
    }
    __syncthreads();

    // ---------- P8: heagg via MFMA (+ t1) ----------
    if (tid < 64) {
        float a = LD<BF16>(p.bp1, tid);
        #pragma unroll 4
        for (int c = 0; c < 32; c++) a += s_cn[c] * LD<BF16>(p.Wp1, c * 64 + tid);
        s_t1[tid] = silu(a);
    }
    {
        f32x4 hg = {};
        #pragma unroll
        for (int ks = 0; ks < 8; ks++) {
            bf16x8 af = *(const bf16x8*)(&s_AT[(wv * 16 + l15) * 272 + ks * 32 + l4 * 8]);
            bf16x8 bfv = *(const bf16x8*)(&s_att[(l15 & 3) * 272 + ks * 32 + l4 * 8]);
            hg = __builtin_amdgcn_mfma_f32_16x16x32_bf16(af, bfv, hg, 0, 0, 0);
        }
        if (l15 < 4) {
            #pragma unroll
            for (int q = 0; q < 4; q++)
                s_heagg[(wv * 16 + l4 * 4 + q) * 4 + l15] = hg[q];
        }
    }
    __syncthreads();

    // ---------- P9: hcomb ----------
    if (tid < 64) {
        float a = LD<BF16>(p.bp2, tid);
        #pragma unroll 4
        for (int k = 0; k < 64; k++) a += s_t1[k] * LD<BF16>(p.Wp2, k * 64 + tid);
        s_hcomb[tid] = a;
    }
    __syncthreads();

    // ---------- P10: node MLP + residual; velocity / coordinates ----------
    {
        int qq = tid >> 6, o = tid & 63;
        int k0 = qq * 96;
        float a = 0.f;
        for (int k2 = k0; k2 < k0 + 96; k2++) {
            float inv;
            if (k2 < 64)       inv = s_rows[3 * 64 + k2];
            else if (k2 < 320) inv = s_heagg[k2 - 64];
            else               inv = s_hcomb[k2 - 320];
            a += inv * LD<BF16>(p.Wn1, k2 * 64 + o);
        }
        s_part[qq * 64 + o] = a;
    }
    __syncthreads();
    if (tid < 64) {
        float a = LD<BF16>(p.bn1, tid) + (s_part[tid] + s_part[64 + tid]) + (s_part[128 + tid] + s_part[192 + tid]);
        s_t1[tid] = silu(a);
    }
    __syncthreads();
    if (tid < 64) {
        float a = LD<BF16>(p.bn2, tid);
        #pragma unroll 4
        for (int k = 0; k < 64; k++) a += s_t1[k] * LD<BF16>(p.Wn2, k * 64 + tid);
        ST<BF16>(p.out, node * 64 + tid, s_rows[3 * 64 + tid] + a);
    } else if (tid < 67) {
        int k = tid - 64;
        float vn = s_dv[k] + s_misc[3] * LD<BF16>(p.v, node * 3 + k);
        float xn = LD<BF16>(p.x, node * 3 + k) + vn;
        ST<BF16>(p.out, 65536 + node * 3 + k, xn);
        ST<BF16>(p.out, 68608 + node * 3 + k, vn);
    }
}

extern "C" void kernel_launch(void* const* d_in, const int* in_sizes, int n_in,
                              void* d_out, int out_size, void* d_ws, size_t ws_size,
                              hipStream_t stream) {
    (void)in_sizes; (void)n_in; (void)out_size; (void)ws_size;
    char* ws = (char*)d_ws;
    float* linj = (float*)(ws + O_LINJ);
    float* lini = (float*)(ws + O_LINI);
    float* vsc  = (float*)(ws + O_VSC);
    u16* we2f = (u16*)(ws + O_WE2F);
    u16* wc1f = (u16*)(ws + O_WC1F);
    u16* wc2f = (u16*)(ws + O_WC2F);
    u32* flag = (u32*)(ws + O_FLAG);

    hipLaunchKernelGGL(sniff_kernel, dim3(1), dim3(64), 0, stream, d_in[0], flag);
    hipLaunchKernelGGL(prep_all, dim3(257), dim3(256), 0, stream,
                       d_in[0], d_in[3], d_in[5], d_in[7], d_in[9], d_in[15],
                       d_in[21], d_in[22], d_in[23],
                       linj, lini, vsc, we2f, wc1f, wc2f, flag);

    Ptrs p;
    p.h   = d_in[0];  p.x   = d_in[1];  p.v   = d_in[2];
    p.We1 = d_in[3];  p.be1 = d_in[4];  p.be2 = d_in[6];
    p.bc1 = d_in[8];  p.bc2 = d_in[10];
    p.Wp1 = d_in[11]; p.bp1 = d_in[12]; p.Wp2 = d_in[13]; p.bp2 = d_in[14];
    p.bs_ = d_in[16];
    p.Wn1 = d_in[17]; p.bn1 = d_in[18]; p.Wn2 = d_in[19]; p.bn2 = d_in[20];
    p.lg  = d_in[24];
    p.linj = linj; p.lini = lini; p.vsc = vsc;
    p.we2f = we2f; p.wc1f = wc1f; p.wc2f = wc2f;
    p.flag = flag;
    p.out = d_out;

    hipLaunchKernelGGL(sake_all<1>, dim3(1024), dim3(256), 0, stream, p);
    hipLaunchKernelGGL(sake_all<0>, dim3(1024), dim3(256), 0, stream, p);
}

// Round 6
// 67.319 us; speedup vs baseline: 5.9504x; 1.0997x over previous
//
#include <hip/hip_runtime.h>

typedef unsigned short u16;
typedef unsigned int   u32;
typedef __attribute__((ext_vector_type(8))) short bf16x8;
typedef __attribute__((ext_vector_type(4))) float f32x4;

#define EPSc 1e-5f
#define INFc 1e5f

// ---------------- ws byte offsets ----------------
#define O_LINJ 0         // f32[1024][64]
#define O_LINI 262144    // f32[1024][64]
#define O_VSC  524288    // f32[1024]
#define O_WE2F 528384    // u16[4*2*64*8]  (cols permuted: c = 4*l15+n)
#define O_WC1F 536576    // u16[5*2*64*8]  (n<4 permuted; tile4 = Ws|0)
#define O_WC2F 546816    // u16[2*2*64*8]  (natural)
#define O_WP1C 550912    // f32[32][64]
#define O_WP2C 559104    // f32[64][64]
#define O_WN2C 575488    // f32[64][64]
#define O_WN1C 591872    // f32[384][64]
#define O_FLAG 690176

struct Ptrs {
    const void *h, *x, *v;
    const void *We1, *be1, *be2;
    const void *bc1, *bc2, *bp1, *bp2, *bs_, *bn1, *bn2, *lg;
    const float *linj, *lini, *vsc;
    const u16 *we2f, *wc1f, *wc2f;
    const float *wp1c, *wp2c, *wn1c, *wn2c;
    const u32 *flag;
    void *out;
};

__device__ __forceinline__ float bfr(u16 u) { return __uint_as_float(((u32)u) << 16); }
__device__ __forceinline__ u16 f2bf(float f) {
    u32 u = __float_as_uint(f);
    u = u + 0x7fffu + ((u >> 16) & 1u);
    return (u16)(u >> 16);
}
__device__ __forceinline__ u32 packbf2(float lo, float hi) {
    return (u32)f2bf(lo) | ((u32)f2bf(hi) << 16);
}
__device__ __forceinline__ float frcp(float x) { return __builtin_amdgcn_rcpf(x); }
__device__ __forceinline__ float silu(float x) { return x * frcp(1.f + __expf(-x)); }
__device__ __forceinline__ float lrelu(float x) { return x > 0.f ? x : 0.2f * x; }

template<int BF16>
__device__ __forceinline__ float LD(const void* p, int i) {
    if constexpr (BF16) return bfr(((const u16*)p)[i]);
    else                return ((const float*)p)[i];
}
template<int BF16>
__device__ __forceinline__ void ST(void* p, int i, float v) {
    if constexpr (BF16) ((u16*)p)[i] = f2bf(v);
    else                ((float*)p)[i] = v;
}
__device__ __forceinline__ float LDr(const void* p, int i, bool bf) {
    return bf ? bfr(((const u16*)p)[i]) : ((const float*)p)[i];
}
__device__ __forceinline__ u16 ENCr(const void* p, int i, bool bf) {
    return bf ? ((const u16*)p)[i] : f2bf(((const float*)p)[i]);
}
#define WAVE_FENCE() do { asm volatile("s_waitcnt lgkmcnt(0)" ::: "memory"); \
                          __builtin_amdgcn_sched_barrier(0); } while (0)

// ---------------- dtype sniffer (proven r3-r5) ----------------
__global__ void sniff_kernel(const void* h, u32* flag) {
    if (threadIdx.x == 0) {
        const u16* ph = (const u16*)h;
        int cnt = 0;
        for (int k = 0; k < 256; k++) {
            float v = bfr(ph[k]);
            float a = fabsf(v);
            if (v == 0.f || (a > 1e-6f && a < 1024.f)) cnt++;
        }
        flag[0] = (cnt >= 224) ? 1u : 0u;
    }
}

// ---------------- prep ----------------
__global__ __launch_bounds__(256) void prep_all(
    const void* h, const void* We1, const void* We2, const void* Wc1,
    const void* Wc2, const void* Ws_, const void* Wp1, const void* Wp2,
    const void* Wn1, const void* Wn2, const void* Wv1, const void* bv1,
    const void* Wv2,
    float* linj, float* lini, float* vsc,
    u16* we2f, u16* wc1f, u16* wc2f,
    float* wp1c, float* wp2c, float* wn1c, float* wn2c, const u32* flag) {
    const bool bf = (flag[0] != 0u);
    const int t = threadIdx.x;
    const int blk = blockIdx.x;
    if (blk == 0) {
        for (int idx = t; idx < 4096; idx += 256) {
            int e = idx & 7, l = (idx >> 3) & 63, ks = (idx >> 9) & 1, nt = idx >> 10;
            int k = ks * 32 + (l >> 4) * 8 + e, c = (l & 15) * 4 + nt;
            we2f[idx] = ENCr(We2, k * 64 + c, bf);
        }
        for (int idx = t; idx < 5120; idx += 256) {
            int e = idx & 7, l = (idx >> 3) & 63, ks = (idx >> 9) & 1, nt = idx >> 10;
            int k = ks * 32 + (l >> 4) * 8 + e;
            u16 v;
            if (nt < 4) v = ENCr(Wc1, k * 64 + (l & 15) * 4 + nt, bf);
            else { int cc = l & 15; v = (cc < 4) ? ENCr(Ws_, k * 4 + cc, bf) : (u16)0; }
            wc1f[idx] = v;
        }
        for (int idx = t; idx < 2048; idx += 256) {
            int e = idx & 7, l = (idx >> 3) & 63, ks = (idx >> 9) & 1, nt = idx >> 10;
            int k = ks * 32 + (l >> 4) * 8 + e, c = nt * 16 + (l & 15);
            wc2f[idx] = ENCr(Wc2, k * 32 + c, bf);
        }
    } else if (blk == 1) {
        for (int idx = t; idx < 2048; idx += 256) wp1c[idx] = LDr(Wp1, idx, bf);
        for (int idx = t; idx < 4096; idx += 256) wp2c[idx] = LDr(Wp2, idx, bf);
        for (int idx = t; idx < 4096; idx += 256) wn2c[idx] = LDr(Wn2, idx, bf);
    } else if (blk == 2) {
        for (int idx = t; idx < 24576; idx += 256) wn1c[idx] = LDr(Wn1, idx, bf);
    } else {
        const int g = t >> 6, tt = t & 63;
        const int n = (blk - 3) * 4 + g;
        __shared__ float hr[4][64];
        hr[g][tt] = LDr(h, n * 64 + tt, bf);
        __syncthreads();
        float a0 = 0.f, a1 = 0.f, a2 = 0.f;
        #pragma unroll 2
        for (int k = 0; k < 64; k++) {
            float hv = hr[g][k];
            a0 += hv * LDr(We1, k * 64 + tt, bf);
            a1 += hv * LDr(We1, (64 + k) * 64 + tt, bf);
            a2 += hv * LDr(Wv1, k * 64 + tt, bf);
        }
        linj[n * 64 + tt] = a0;
        lini[n * 64 + tt] = a1;
        float pv = silu(a2 + LDr(bv1, tt, bf)) * LDr(Wv2, tt, bf);
        #pragma unroll
        for (int o = 32; o; o >>= 1) pv += __shfl_down(pv, o);
        if (tt == 0) vsc[n] = pv;
    }
}

// N-channel block reduction over 256 threads (4 waves)
template<int N>
__device__ __forceinline__ void blk_red(float v[N], bool domax, float* scr, int tid) {
    #pragma unroll
    for (int s2 = 32; s2; s2 >>= 1)
        #pragma unroll
        for (int u = 0; u < N; u++) {
            float o = __shfl_xor(v[u], s2);
            v[u] = domax ? fmaxf(v[u], o) : (v[u] + o);
        }
    __syncthreads();
    if ((tid & 63) == 0) {
        int w = tid >> 6;
        #pragma unroll
        for (int u = 0; u < N; u++) scr[w * N + u] = v[u];
    }
    __syncthreads();
    #pragma unroll
    for (int u = 0; u < N; u++) {
        float a = scr[0 * N + u], b2 = scr[1 * N + u], c = scr[2 * N + u], d = scr[3 * N + u];
        v[u] = domax ? fmaxf(fmaxf(a, b2), fmaxf(c, d)) : ((a + b2) + (c + d));
    }
}

// ---------------- main fused kernel: one block per (b,i) ----------------
template<int BF16>
__global__ __launch_bounds__(256, 3) void sake_all(Ptrs p) {
    if ((p.flag[0] != 0u) != (BF16 != 0)) return;

    const int node = blockIdx.x;
    const int i = node & 255;
    const int b = node >> 8;
    const int tid = threadIdx.x;
    const int j = tid;
    const int lane = tid & 63, wv = tid >> 6;
    const int l15 = lane & 15, l4 = lane >> 4;

    // ---- LDS 53,680 B -> 3 blocks/CU ----
    __shared__ alignas(16) u16 s_A[256 * 72];     // spre/he [j][h] stride 72; later s_AT [64][280]
    __shared__ alignas(16) u16 s_wsq[4 * 16 * 72];// c1 tiles; later s_nin[384]|s_t1[64]|s_part[256] f32
    __shared__ alignas(16) u16 s_xs[256 * 4];     // bf16 {xs0,xs1,xs2,nrm}
    __shared__ alignas(8)  u16 s_sa[256 * 4];     // bf16 semantic logits
    __shared__ alignas(16) u16 s_att[4 * 272];    // combw f32 alias -> attT bf16 [4][272]
    __shared__ float s_rows[4 * 64];              // we1last | be1 | lin_i | h_i
    __shared__ float s_cn[32];
    __shared__ float s_dv[4];
    __shared__ float s_scr[32];
    __shared__ float s_misc[8];                   // x_i | vsc | exp(lg)

    u16*   s_AT    = s_A;                           // [64][280]
    float* s_nin   = (float*)s_wsq;                 // [384] node-MLP input
    float* s_t1    = (float*)((char*)s_wsq + 1536); // [64]
    float* s_part  = (float*)((char*)s_wsq + 1792); // [4][64]
    float* s_combw = (float*)s_att;                 // [4][32][3]

    // early: We2 fragment loads (coalesced b128, L2-broadcast)
    bf16x8 bw2[2][4];
    #pragma unroll
    for (int n = 0; n < 4; n++)
        #pragma unroll
        for (int ks = 0; ks < 2; ks++)
            bw2[ks][n] = *(const bf16x8*)(p.we2f + ((n * 2 + ks) * 64 + lane) * 8);
    float be2v[4];
    #pragma unroll
    for (int n = 0; n < 4; n++) be2v[n] = LD<BF16>(p.be2, 4 * l15 + n);

    // ---------- P0: stage ----------
    if (tid < 64) {
        s_rows[0 * 64 + tid] = LD<BF16>(p.We1, 128 * 64 + tid);
        s_rows[1 * 64 + tid] = LD<BF16>(p.be1, tid);
        s_rows[2 * 64 + tid] = p.lini[node * 64 + tid];
        s_rows[3 * 64 + tid] = LD<BF16>(p.h, node * 64 + tid);
    } else if (tid < 67) {
        s_misc[tid - 64] = LD<BF16>(p.x, node * 3 + (tid - 64));
    } else if (tid == 67) {
        s_misc[3] = p.vsc[node];
    } else if (tid < 72) {
        s_misc[4 + (tid - 68)] = __expf(LD<BF16>(p.lg, tid - 68));
    }
    __syncthreads();   // B1

    // ---------- P1: xs + spre (wave-local rows) ----------
    float nrm;
    {
        float d0 = LD<BF16>(p.x, (b * 256 + j) * 3 + 0) - s_misc[0];
        float d1 = LD<BF16>(p.x, (b * 256 + j) * 3 + 1) - s_misc[1];
        float d2 = LD<BF16>(p.x, (b * 256 + j) * 3 + 2) - s_misc[2];
        nrm = sqrtf(d0 * d0 + d1 * d1 + d2 * d2 + EPSc);
        float den = nrm + EPSc;
        float invd = frcp(den * den);
        uint2 xw;
        xw.x = packbf2(d0 * invd, d1 * invd);
        xw.y = packbf2(d2 * invd, nrm);
        *(uint2*)(&s_xs[j * 4]) = xw;

        const f32x4* lj = (const f32x4*)(p.linj + (b * 256 + j) * 64);
        #pragma unroll
        for (int c = 0; c < 8; c++) {
            f32x4 a = lj[2 * c], bq = lj[2 * c + 1];
            float s[8];
            #pragma unroll
            for (int e = 0; e < 4; e++) {
                int o = c * 8 + e;
                s[e] = silu(a[e] + s_rows[128 + o] + nrm * s_rows[o] + s_rows[64 + o]);
            }
            #pragma unroll
            for (int e = 0; e < 4; e++) {
                int o = c * 8 + 4 + e;
                s[4 + e] = silu(bq[e] + s_rows[128 + o] + nrm * s_rows[o] + s_rows[64 + o]);
            }
            uint4 w;
            w.x = packbf2(s[0], s[1]); w.y = packbf2(s[2], s[3]);
            w.z = packbf2(s[4], s[5]); w.w = packbf2(s[6], s[7]);
            *(uint4*)(&s_A[j * 72 + c * 8]) = w;
        }
    }
    WAVE_FENCE();   // P1 writes -> GEMM1 reads (same wave's rows)

    // ---------- GEMM1: he_pre = spre @ We2 (permuted cols) ----------
    f32x4 acc[4][4] = {};
    #pragma unroll
    for (int mt = 0; mt < 4; mt++) {
        int row = (wv * 4 + mt) * 16 + l15;
        #pragma unroll
        for (int ks = 0; ks < 2; ks++) {
            bf16x8 a = *(const bf16x8*)(&s_A[row * 72 + ks * 32 + l4 * 8]);
            #pragma unroll
            for (int n = 0; n < 4; n++)
                acc[mt][n] = __builtin_amdgcn_mfma_f32_16x16x32_bf16(a, bw2[ks][n], acc[mt][n], 0, 0, 0);
        }
    }
    WAVE_FENCE();   // all this wave's reads done before overwrite
    // ---------- P2: he writeback, packed b64 (cols 4*l15..+3 natural order) ----------
    #pragma unroll
    for (int mt = 0; mt < 4; mt++)
        #pragma unroll
        for (int q = 0; q < 4; q++) {
            int row = (wv * 4 + mt) * 16 + l4 * 4 + q;
            uint2 pk;
            pk.x = packbf2(silu(acc[mt][0][q] + be2v[0]), silu(acc[mt][1][q] + be2v[1]));
            pk.y = packbf2(silu(acc[mt][2][q] + be2v[2]), silu(acc[mt][3][q] + be2v[3]));
            *(uint2*)(&s_A[row * 72 + 4 * l15]) = pk;
        }
    WAVE_FENCE();   // he writes -> S4 reads (same wave's rows)

    // ---------- S4: GEMM2 (+logits tile) and GEMM3, cmb ----------
    {
        bf16x8 bw3[2][5], bw4[2][2];
        #pragma unroll
        for (int n = 0; n < 5; n++)
            #pragma unroll
            for (int ks = 0; ks < 2; ks++)
                bw3[ks][n] = *(const bf16x8*)(p.wc1f + ((n * 2 + ks) * 64 + lane) * 8);
        #pragma unroll
        for (int n = 0; n < 2; n++)
            #pragma unroll
            for (int ks = 0; ks < 2; ks++)
                bw4[ks][n] = *(const bf16x8*)(p.wc2f + ((n * 2 + ks) * 64 + lane) * 8);
        float bc1v[4], bc2v[2];
        #pragma unroll
        for (int n = 0; n < 4; n++) bc1v[n] = LD<BF16>(p.bc1, 4 * l15 + n);
        #pragma unroll
        for (int n = 0; n < 2; n++) bc2v[n] = LD<BF16>(p.bc2, n * 16 + l15);
        float bsv = LD<BF16>(p.bs_, l15 & 3);

        u16* myws = s_wsq + wv * (16 * 72);
        float cmb[2][3] = {};
        #pragma unroll 1
        for (int mt = 0; mt < 4; mt++) {
            f32x4 c1x[5] = {};
            #pragma unroll
            for (int ks = 0; ks < 2; ks++) {
                bf16x8 a = *(const bf16x8*)(&s_A[((wv * 4 + mt) * 16 + l15) * 72 + ks * 32 + l4 * 8]);
                #pragma unroll
                for (int n = 0; n < 5; n++)
                    c1x[n] = __builtin_amdgcn_mfma_f32_16x16x32_bf16(a, bw3[ks][n], c1x[n], 0, 0, 0);
            }
            #pragma unroll
            for (int q = 0; q < 4; q++) {
                uint2 pk;
                pk.x = packbf2(silu(c1x[0][q] + bc1v[0]), silu(c1x[1][q] + bc1v[1]));
                pk.y = packbf2(silu(c1x[2][q] + bc1v[2]), silu(c1x[3][q] + bc1v[3]));
                *(uint2*)(&myws[(l4 * 4 + q) * 72 + 4 * l15]) = pk;
            }
            if (l15 < 4) {
                #pragma unroll
                for (int q = 0; q < 4; q++) {
                    int row = wv * 64 + mt * 16 + l4 * 4 + q;
                    float sub = (row == i) ? INFc : 0.f;
                    s_sa[row * 4 + l15] = f2bf(lrelu(c1x[4][q] + bsv) - sub);
                }
            }
            WAVE_FENCE();
            f32x4 co[2] = {};
            #pragma unroll
            for (int ks = 0; ks < 2; ks++) {
                bf16x8 a2 = *(const bf16x8*)(&myws[l15 * 72 + ks * 32 + l4 * 8]);
                #pragma unroll
                for (int n = 0; n < 2; n++)
                    co[n] = __builtin_amdgcn_mfma_f32_16x16x32_bf16(a2, bw4[ks][n], co[n], 0, 0, 0);
            }
            #pragma unroll
            for (int q = 0; q < 4; q++) {
                int r = wv * 64 + mt * 16 + l4 * 4 + q;
                uint2 xw = *(const uint2*)(&s_xs[r * 4]);
                float x0 = __uint_as_float(xw.x << 16);
                float x1 = __uint_as_float(xw.x & 0xffff0000u);
                float x2 = __uint_as_float(xw.y << 16);
                #pragma unroll
                for (int n = 0; n < 2; n++) {
                    float c = co[n][q] + bc2v[n];
                    cmb[n][0] += c * x0;
                    cmb[n][1] += c * x1;
                    cmb[n][2] += c * x2;
                }
            }
        }
        #pragma unroll
        for (int n = 0; n < 2; n++)
            #pragma unroll
            for (int k = 0; k < 3; k++) {
                float v = cmb[n][k];
                v += __shfl_xor(v, 16);
                v += __shfl_xor(v, 32);
                cmb[n][k] = v;
            }
        if (l4 == 0) {
            #pragma unroll
            for (int n = 0; n < 2; n++)
                #pragma unroll
                for (int k = 0; k < 3; k++)
                    s_combw[(wv * 32 + n * 16 + l15) * 3 + k] = cmb[n][k];
        }
    }
    __syncthreads();   // B2: s_combw cross-wave

    // ---------- S5: read he rows + comb_norm/delta_v ----------
    uint4 her[8];
    #pragma unroll
    for (int c = 0; c < 8; c++) her[c] = *(const uint4*)(&s_A[j * 72 + c * 8]);
    float cnv = 0.f, dvv = 0.f;
    if (tid < 32) {
        float c0 = 0.f, c1 = 0.f, c2 = 0.f;
        #pragma unroll
        for (int w = 0; w < 4; w++) {
            c0 += s_combw[(w * 32 + tid) * 3 + 0];
            c1 += s_combw[(w * 32 + tid) * 3 + 1];
            c2 += s_combw[(w * 32 + tid) * 3 + 2];
        }
        cnv = c0 * c0 + c1 * c1 + c2 * c2;
    } else if (tid < 35) {
        int k = tid - 32;
        float a = 0.f;
        for (int w = 0; w < 4; w++)
            #pragma unroll 8
            for (int c = 0; c < 32; c++) a += s_combw[(w * 32 + c) * 3 + k];
        dvv = a * (1.0f / 8192.f);
    }
    __syncthreads();   // B3: WAR (he reads before AT overwrite)

    // ---------- S6: transpose-write s_AT [64][280] + cn/dv ----------
    #pragma unroll
    for (int c = 0; c < 8; c++) {
        u32 d[4] = { her[c].x, her[c].y, her[c].z, her[c].w };
        #pragma unroll
        for (int dw = 0; dw < 4; dw++) {
            int hh = c * 8 + dw * 2;
            s_AT[hh * 280 + j]       = (u16)(d[dw] & 0xffffu);
            s_AT[(hh + 1) * 280 + j] = (u16)(d[dw] >> 16);
        }
    }
    if (tid < 32) s_cn[tid] = cnv;
    else if (tid < 35) s_dv[tid - 32] = dvv;

    // ---------- P7: softmaxes (att_e needs no max: logits <= 0) ----------
    {
        float pen = (j == i) ? INFc : 0.f;
        float elb = -(nrm + pen);
        float ge[4] = { s_misc[4], s_misc[5], s_misc[6], s_misc[7] };
        float sl[4];
        #pragma unroll
        for (int u = 0; u < 4; u++) sl[u] = bfr(s_sa[j * 4 + u]);

        float r4a[4] = { sl[0], sl[1], sl[2], sl[3] };
        blk_red<4>(r4a, true, s_scr, tid);      // B4,B5

        float ae[4], as_[4];
        #pragma unroll
        for (int u = 0; u < 4; u++) ae[u] = __expf(ge[u] * elb);
        #pragma unroll
        for (int u = 0; u < 4; u++) as_[u] = __expf(sl[u] - r4a[u]);

        float r8[8] = { ae[0], ae[1], ae[2], ae[3], as_[0], as_[1], as_[2], as_[3] };
        blk_red<8>(r8, false, s_scr, tid);      // B6,B7

        float ep[4];
        #pragma unroll
        for (int u = 0; u < 4; u++)
            ep[u] = __expf(ae[u] * frcp(r8[u]) * as_[u] * frcp(r8[4 + u]));
        float r4b[4] = { ep[0], ep[1], ep[2], ep[3] };
        blk_red<4>(r4b, false, s_scr, tid);     // B8,B9
        #pragma unroll
        for (int u = 0; u < 4; u++)
            s_att[u * 272 + j] = f2bf(ep[u] * frcp(r4b[u]));
    }
    __syncthreads();   // B10: att + AT ready

    // ---------- P8: heagg via MFMA (all waves) + t1 (wave0) + h-copy (wave1) ----------
    {
        f32x4 hg = {};
        #pragma unroll
        for (int ks = 0; ks < 8; ks++) {
            bf16x8 af = *(const bf16x8*)(&s_AT[(wv * 16 + l15) * 280 + ks * 32 + l4 * 8]);
            bf16x8 bfv = *(const bf16x8*)(&s_att[(l15 & 3) * 272 + ks * 32 + l4 * 8]);
            hg = __builtin_amdgcn_mfma_f32_16x16x32_bf16(af, bfv, hg, 0, 0, 0);
        }
        if (l15 < 4) {
            #pragma unroll
            for (int q = 0; q < 4; q++)
                s_nin[64 + (wv * 16 + l4 * 4 + q) * 4 + l15] = hg[q];
        }
    }
    if (wv == 0) {           // t1 = silu(bp1 + cn @ Wp1)
        float a[4] = {};
        #pragma unroll
        for (int e = 0; e < 8; e++) {
            int c = l4 * 8 + e;
            f32x4 w4 = *(const f32x4*)(p.wp1c + c * 64 + 4 * l15);
            float cv = s_cn[c];
            #pragma unroll
            for (int n = 0; n < 4; n++) a[n] += cv * w4[n];
        }
        #pragma unroll
        for (int n = 0; n < 4; n++) {
            a[n] += __shfl_xor(a[n], 16);
            a[n] += __shfl_xor(a[n], 32);
        }
        if (l4 == 0) {
            f32x4 tv;
            #pragma unroll
            for (int n = 0; n < 4; n++) tv[n] = silu(a[n] + LD<BF16>(p.bp1, 4 * l15 + n));
            *(f32x4*)(&s_t1[4 * l15]) = tv;
        }
    } else if (wv == 1) {    // copy h_i into s_nin[0..64)
        s_nin[lane] = s_rows[192 + lane];
    }
    __syncthreads();   // B11

    // ---------- P9: hcomb (wave2) + node-MLP parts (all waves) ----------
    if (wv == 2) {           // hcomb = bp2 + t1 @ Wp2 -> s_nin[320..384)
        float a[4] = {};
        #pragma unroll
        for (int it = 0; it < 16; it++) {
            int k = l4 * 16 + it;
            f32x4 w4 = *(const f32x4*)(p.wp2c + k * 64 + 4 * l15);
            float tk = s_t1[k];
            #pragma unroll
            for (int n = 0; n < 4; n++) a[n] += tk * w4[n];
        }
        #pragma unroll
        for (int n = 0; n < 4; n++) {
            a[n] += __shfl_xor(a[n], 16);
            a[n] += __shfl_xor(a[n], 32);
        }
        if (l4 == 0) {
            f32x4 hv;
            #pragma unroll
            for (int n = 0; n < 4; n++) hv[n] = a[n] + LD<BF16>(p.bp2, 4 * l15 + n);
            *(f32x4*)(&s_nin[320 + 4 * l15]) = hv;
        }
        WAVE_FENCE();        // wave2's own nin writes before its part reads
    }
    {
        const int Q = (wv == 0) ? 0 : (wv == 1) ? 96 : (wv == 2) ? 288 : 192;
        int k0 = Q + l4 * 24;
        float a[4] = {};
        #pragma unroll
        for (int it = 0; it < 6; it++) {
            f32x4 inv = *(const f32x4*)(&s_nin[k0 + it * 4]);
            #pragma unroll
            for (int r = 0; r < 4; r++) {
                f32x4 w4 = *(const f32x4*)(p.wn1c + (k0 + it * 4 + r) * 64 + 4 * l15);
                #pragma unroll
                for (int n = 0; n < 4; n++) a[n] += inv[r] * w4[n];
            }
        }
        #pragma unroll
        for (int n = 0; n < 4; n++) {
            a[n] += __shfl_xor(a[n], 16);
            a[n] += __shfl_xor(a[n], 32);
        }
        if (l4 == 0) {
            f32x4 pv = { a[0], a[1], a[2], a[3] };
            *(f32x4*)(&s_part[wv * 64 + 4 * l15]) = pv;
        }
    }
    __syncthreads();   // B12

    // ---------- P10: finish (wave0) + x/v outputs (wave1) ----------
    if (wv == 0) {
        float v2 = LD<BF16>(p.bn1, lane) + (s_part[lane] + s_part[64 + lane])
                 + (s_part[128 + lane] + s_part[192 + lane]);
        s_t1[lane] = silu(v2);
        WAVE_FENCE();
        float a[4] = {};
        #pragma unroll
        for (int it = 0; it < 16; it++) {
            int k = l4 * 16 + it;
            f32x4 w4 = *(const f32x4*)(p.wn2c + k * 64 + 4 * l15);
            float tk = s_t1[k];
            #pragma unroll
            for (int n = 0; n < 4; n++) a[n] += tk * w4[n];
        }
        #pragma unroll
        for (int n = 0; n < 4; n++) {
            a[n] += __shfl_xor(a[n], 16);
            a[n] += __shfl_xor(a[n], 32);
        }
        if (l4 == 0) {
            #pragma unroll
            for (int n = 0; n < 4; n++) {
                int o = 4 * l15 + n;
                ST<BF16>(p.out, node * 64 + o,
                         s_rows[192 + o] + LD<BF16>(p.bn2, o) + a[n]);
            }
        }
    } else if (wv == 1 && lane < 3) {
        int k = lane;
        float vn = s_dv[k] + s_misc[3] * LD<BF16>(p.v, node * 3 + k);
        float xn = LD<BF16>(p.x, node * 3 + k) + vn;
        ST<BF16>(p.out, 65536 + node * 3 + k, xn);
        ST<BF16>(p.out, 68608 + node * 3 + k, vn);
    }
}

extern "C" void kernel_launch(void* const* d_in, const int* in_sizes, int n_in,
                              void* d_out, int out_size, void* d_ws, size_t ws_size,
                              hipStream_t stream) {
    (void)in_sizes; (void)n_in; (void)out_size; (void)ws_size;
    char* ws = (char*)d_ws;
    float* linj = (float*)(ws + O_LINJ);
    float* lini = (float*)(ws + O_LINI);
    float* vsc  = (float*)(ws + O_VSC);
    u16* we2f = (u16*)(ws + O_WE2F);
    u16* wc1f = (u16*)(ws + O_WC1F);
    u16* wc2f = (u16*)(ws + O_WC2F);
    float* wp1c = (float*)(ws + O_WP1C);
    float* wp2c = (float*)(ws + O_WP2C);
    float* wn2c = (float*)(ws + O_WN2C);
    float* wn1c = (float*)(ws + O_WN1C);
    u32* flag = (u32*)(ws + O_FLAG);

    hipLaunchKernelGGL(sniff_kernel, dim3(1), dim3(64), 0, stream, d_in[0], flag);
    hipLaunchKernelGGL(prep_all, dim3(259), dim3(256), 0, stream,
                       d_in[0], d_in[3], d_in[5], d_in[7], d_in[9], d_in[15],
                       d_in[11], d_in[13], d_in[17], d_in[19],
                       d_in[21], d_in[22], d_in[23],
                       linj, lini, vsc, we2f, wc1f, wc2f,
                       wp1c, wp2c, wn1c, wn2c, flag);

    Ptrs p;
    p.h   = d_in[0];  p.x   = d_in[1];  p.v   = d_in[2];
    p.We1 = d_in[3];  p.be1 = d_in[4];  p.be2 = d_in[6];
    p.bc1 = d_in[8];  p.bc2 = d_in[10];
    p.bp1 = d_in[12]; p.bp2 = d_in[14];
    p.bs_ = d_in[16];
    p.bn1 = d_in[18]; p.bn2 = d_in[20];
    p.lg  = d_in[24];
    p.linj = linj; p.lini = lini; p.vsc = vsc;
    p.we2f = we2f; p.wc1f = wc1f; p.wc2f = wc2f;
    p.wp1c = wp1c; p.wp2c = wp2c; p.wn1c = wn1c; p.wn2c = wn2c;
    p.flag = flag;
    p.out = d_out;

    hipLaunchKernelGGL(sake_all<1>, dim3(1024), dim3(256), 0, stream, p);
    hipLaunchKernelGGL(sake_all<0>, dim3(1024), dim3(256), 0, stream, p);
}